// Round 2
// baseline (3437.947 us; speedup 1.0000x reference)
//
#include <hip/hip_runtime.h>
#include <hip/hip_bf16.h>

#define S_LEN 2048
#define D_DIM 1024
#define H_NUM 16
#define HD_DIM 64
#define GH_DIM 64
#define FFN_H 2730
#define CTX_W 512
#define LAM 0.999f

__device__ inline float wave_sum(float v) {
    for (int off = 32; off; off >>= 1) v += __shfl_xor(v, off);
    return v;
}

// ---------------- RMSNorm: one block per row, 256 threads, float4 ----------
__global__ __launch_bounds__(256) void rmsnorm_kernel(const float* __restrict__ in,
    const float* __restrict__ w, float* __restrict__ out)
{
    int row = blockIdx.x;
    const float4* ir = reinterpret_cast<const float4*>(in + (size_t)row * D_DIM);
    float4 v = ir[threadIdx.x];
    float ss = v.x*v.x + v.y*v.y + v.z*v.z + v.w*v.w;
    ss = wave_sum(ss);
    __shared__ float wsum[4];
    if ((threadIdx.x & 63) == 0) wsum[threadIdx.x >> 6] = ss;
    __syncthreads();
    float tot = wsum[0] + wsum[1] + wsum[2] + wsum[3];
    float scale = rsqrtf(tot / (float)D_DIM + 1e-6f);
    const float4* wr = reinterpret_cast<const float4*>(w);
    float4 wv = wr[threadIdx.x];
    float4 o;
    o.x = v.x * scale * wv.x; o.y = v.y * scale * wv.y;
    o.z = v.z * scale * wv.z; o.w = v.w * scale * wv.w;
    reinterpret_cast<float4*>(out + (size_t)row * D_DIM)[threadIdx.x] = o;
}

// ---------------- Generic fp32 GEMM: C = [res +] A(MxK) @ B(KxN) -----------
#define TM 64
#define TN 64
#define TK 16
__global__ __launch_bounds__(256) void gemm_kernel(const float* __restrict__ A,
    const float* __restrict__ B, const float* __restrict__ res,
    float* __restrict__ C, int M, int N, int K)
{
    __shared__ __align__(16) float As[TK][TM + 4];
    __shared__ __align__(16) float Bs[TK][TN + 4];
    int tx = threadIdx.x & 15;
    int ty = threadIdx.x >> 4;
    int row0 = blockIdx.y * TM;
    int col0 = blockIdx.x * TN;
    float c[4][4] = {};
    for (int k0 = 0; k0 < K; k0 += TK) {
        for (int l = threadIdx.x; l < TM * TK; l += 256) {
            int r = l >> 4, kk = l & 15;
            int gr = row0 + r, gk = k0 + kk;
            float v = 0.f;
            if (gr < M && gk < K) v = A[(size_t)gr * K + gk];
            As[kk][r] = v;
        }
        for (int l = threadIdx.x; l < TK * TN; l += 256) {
            int kk = l >> 6, cc = l & 63;
            int gc = col0 + cc, gk = k0 + kk;
            float v = 0.f;
            if (gk < K && gc < N) v = B[(size_t)gk * N + gc];
            Bs[kk][cc] = v;
        }
        __syncthreads();
        #pragma unroll
        for (int kk = 0; kk < TK; ++kk) {
            float4 a = *reinterpret_cast<const float4*>(&As[kk][ty * 4]);
            float4 b = *reinterpret_cast<const float4*>(&Bs[kk][tx * 4]);
            float av[4] = {a.x, a.y, a.z, a.w};
            float bv[4] = {b.x, b.y, b.z, b.w};
            #pragma unroll
            for (int i = 0; i < 4; ++i)
                #pragma unroll
                for (int j = 0; j < 4; ++j)
                    c[i][j] += av[i] * bv[j];
        }
        __syncthreads();
    }
    #pragma unroll
    for (int i = 0; i < 4; ++i) {
        int gr = row0 + ty * 4 + i;
        if (gr >= M) continue;
        #pragma unroll
        for (int j = 0; j < 4; ++j) {
            int gc = col0 + tx * 4 + j;
            if (gc >= N) continue;
            float v = c[i][j];
            if (res) v += res[(size_t)gr * N + gc];
            C[(size_t)gr * N + gc] = v;
        }
    }
}

// ------------- split qkv + qk rmsnorm + RoPE; layout (H, S, HD) ------------
__global__ __launch_bounds__(64) void split_rope_kernel(
    const float* __restrict__ qkv, const float* __restrict__ qw,
    const float* __restrict__ kw, float* __restrict__ qhp,
    float* __restrict__ khp, float* __restrict__ vhp)
{
    int s = blockIdx.x, h = blockIdx.y, d = threadIdx.x;
    size_t base = (size_t)s * (3 * D_DIM) + h * HD_DIM + d;
    float qv = qkv[base];
    float kv = qkv[base + D_DIM];
    float vv = qkv[base + 2 * D_DIM];
    float sq = wave_sum(qv * qv);
    float qn = qv * rsqrtf(sq / (float)HD_DIM + 1e-6f) * qw[d];
    float sk = wave_sum(kv * kv);
    float kn = kv * rsqrtf(sk / (float)HD_DIM + 1e-6f) * kw[d];
    int j = d & 31;
    float inv = expf(-(float)j * (9.2103403719761836f / 32.0f)); // 10000^(-j/32)
    float ang = (float)s * inv;
    float cs = cosf(ang), sn = sinf(ang);
    float qp = __shfl_xor(qn, 32);
    float kp = __shfl_xor(kn, 32);
    float sgn = (d < 32) ? -1.f : 1.f;
    float qo = qn * cs + sgn * qp * sn;
    float ko = kn * cs + sgn * kp * sn;
    size_t ob = ((size_t)h * S_LEN + s) * HD_DIM + d;
    qhp[ob] = qo; khp[ob] = ko; vhp[ob] = vv;
}

// ------------- gamma gate: sigmoid(silu(h@W1)@W2) per token ----------------
__global__ __launch_bounds__(64) void gamma_kernel(const float* __restrict__ h,
    const float* __restrict__ w1, const float* __restrict__ w2,
    float* __restrict__ gamma)
{
    __shared__ float hl[D_DIM];
    int s = blockIdx.x, j = threadIdx.x;
    for (int k = j; k < D_DIM; k += 64) hl[k] = h[(size_t)s * D_DIM + k];
    __syncthreads();
    float acc = 0.f;
    for (int k = 0; k < D_DIM; ++k) acc += hl[k] * w1[k * GH_DIM + j];
    float z = acc / (1.f + expf(-acc));     // silu
    float y = z * w2[j];
    float tot = wave_sum(y);
    if (j == 0) gamma[s] = 1.f / (1.f + expf(-tot));
}

__global__ void fill_decay_kernel(float* __restrict__ decay) {
    int i = threadIdx.x;
    if (i < CTX_W) decay[i] = powf(LAM, (float)i);
}

// ------------- omega-rule memory update (in-place on qh) -------------------
__global__ __launch_bounds__(64) void omega_kernel(
    float* __restrict__ qhp, const float* __restrict__ khp,
    const float* __restrict__ gamma, const float* __restrict__ decay,
    const float* __restrict__ mp, const float* __restrict__ mg)
{
    __shared__ float ql[HD_DIM];
    __shared__ float cl[CTX_W];
    int t = blockIdx.x, h = blockIdx.y, d = threadIdx.x;
    size_t qoff = ((size_t)h * S_LEN + t) * HD_DIM;
    float qd = qhp[qoff + d];
    ql[d] = qd;
    __syncthreads();
    // persist_d = sum_e m_persist[h,d,e] * q[e]
    const float* mrow = mp + ((size_t)h * HD_DIM + d) * HD_DIM;
    float pd = 0.f;
    #pragma unroll 8
    for (int e = 0; e < HD_DIM; ++e) pd += mrow[e] * ql[e];
    int i0 = t - (CTX_W - 1); if (i0 < 0) i0 = 0;
    float wsum = 0.f;
    for (int i = i0 + d; i <= t; i += 64) {
        const float* kr = khp + ((size_t)h * S_LEN + i) * HD_DIM;
        float dot = 0.f;
        #pragma unroll 8
        for (int e = 0; e < HD_DIM; ++e) dot += ql[e] * kr[e];
        float wi = decay[t - i] * gamma[i];
        cl[i - i0] = wi * dot;
        wsum += wi;
    }
    wsum = wave_sum(wsum);
    __syncthreads();
    int nw = t - i0 + 1;
    float contrib = 0.f;
    for (int idx = 0; idx < nw; ++idx)
        contrib += cl[idx] * khp[((size_t)h * S_LEN + i0 + idx) * HD_DIM + d];
    float norm = 1.f + wsum;
    float g = 1.f / (1.f + expf(-mg[0]));
    float qnew = (1.f - g) * qd + g * (pd + contrib) / norm;
    qhp[qoff + d] = qnew;
}

// ------------- causal attention, one block per (t, h) ----------------------
__global__ __launch_bounds__(256) void attn_kernel(const float* __restrict__ qhp,
    const float* __restrict__ khp, const float* __restrict__ vhp,
    float* __restrict__ ao)
{
    __shared__ float ql[HD_DIM];
    __shared__ float logits[S_LEN];
    __shared__ float red[256];
    __shared__ float psum[4][HD_DIM];
    int t = blockIdx.x, h = blockIdx.y;
    const float* qrow = qhp + ((size_t)h * S_LEN + t) * HD_DIM;
    if (threadIdx.x < HD_DIM) ql[threadIdx.x] = qrow[threadIdx.x];
    __syncthreads();
    float lmax = -1e30f;
    for (int i = threadIdx.x; i <= t; i += 256) {
        const float* kr = khp + ((size_t)h * S_LEN + i) * HD_DIM;
        float dot = 0.f;
        #pragma unroll 8
        for (int d = 0; d < HD_DIM; ++d) dot += ql[d] * kr[d];
        dot *= 0.125f;
        logits[i] = dot;
        lmax = fmaxf(lmax, dot);
    }
    red[threadIdx.x] = lmax; __syncthreads();
    for (int s2 = 128; s2; s2 >>= 1) {
        if (threadIdx.x < s2) red[threadIdx.x] = fmaxf(red[threadIdx.x], red[threadIdx.x + s2]);
        __syncthreads();
    }
    float m = red[0];
    __syncthreads();
    float lsum = 0.f;
    for (int i = threadIdx.x; i <= t; i += 256) {
        float e = expf(logits[i] - m);
        logits[i] = e;
        lsum += e;
    }
    red[threadIdx.x] = lsum; __syncthreads();
    for (int s2 = 128; s2; s2 >>= 1) {
        if (threadIdx.x < s2) red[threadIdx.x] += red[threadIdx.x + s2];
        __syncthreads();
    }
    float Z = red[0];
    __syncthreads();
    int d = threadIdx.x & 63, part = threadIdx.x >> 6;
    float acc = 0.f;
    for (int i = part; i <= t; i += 4)
        acc += logits[i] * vhp[((size_t)h * S_LEN + i) * HD_DIM + d];
    psum[part][d] = acc;
    __syncthreads();
    if (threadIdx.x < HD_DIM) {
        float o = (psum[0][d] + psum[1][d] + psum[2][d] + psum[3][d]) / Z;
        ao[(size_t)t * D_DIM + h * HD_DIM + d] = o;
    }
}

// ------------- SwiGLU elementwise ------------------------------------------
__global__ void silumul_kernel(const float* __restrict__ g1,
    const float* __restrict__ g3, float* __restrict__ out, int n)
{
    int i = blockIdx.x * blockDim.x + threadIdx.x;
    if (i < n) {
        float a = g1[i];
        out[i] = a / (1.f + expf(-a)) * g3[i];
    }
}

extern "C" void kernel_launch(void* const* d_in, const int* in_sizes, int n_in,
                              void* d_out, int out_size, void* d_ws, size_t ws_size,
                              hipStream_t stream) {
    const float* x         = (const float*)d_in[0];
    const float* norm1_w   = (const float*)d_in[1];
    const float* norm2_w   = (const float*)d_in[2];
    const float* w_qkv     = (const float*)d_in[3];
    const float* q_norm_w  = (const float*)d_in[4];
    const float* k_norm_w  = (const float*)d_in[5];
    const float* gamma_w1  = (const float*)d_in[6];
    const float* gamma_w2  = (const float*)d_in[7];
    const float* m_persist = (const float*)d_in[8];
    const float* mem_gate  = (const float*)d_in[9];
    const float* w_o       = (const float*)d_in[10];
    const float* ffn_w1    = (const float*)d_in[11];
    const float* ffn_w3    = (const float*)d_in[12];
    const float* ffn_w2    = (const float*)d_in[13];
    float* out = (float*)d_out;
    char* ws = (char*)d_ws;

    const size_t MB = 1024 * 1024;
    // Workspace layout (no trailing-backslash comments -- they splice lines!)
    float* h_buf  = (float*)(ws);            // [0,  8MB): h, later h2
    float* qkv    = (float*)(ws + 8  * MB);  // [8, 32MB): qkv; later ao; later G1
    float* qh     = (float*)(ws + 32 * MB);  // [32,40MB): q (H,S,HD); later G3 start
    float* kh     = (float*)(ws + 40 * MB);  // [40,48MB): k (H,S,HD)
    float* vh     = (float*)(ws + 48 * MB);  // [48,56MB): v (H,S,HD)
    float* gammab = (float*)(ws + 56 * MB);  // 8KB gamma per token
    float* decay  = gammab + S_LEN;          // 2KB lambda^delta table
    float* ao = qkv;   // qkv dead after split_rope
    float* G1 = qkv;   // ao dead after w_o gemm; 22.4MB fits in 24MB region
    float* G3 = qh;    // q/k/v dead after attention; 22.4MB fits in 24MB region

    // 1. h = rms(x, norm1_w)
    hipLaunchKernelGGL(rmsnorm_kernel, dim3(S_LEN), dim3(256), 0, stream, x, norm1_w, h_buf);
    // decay table
    hipLaunchKernelGGL(fill_decay_kernel, dim3(1), dim3(512), 0, stream, decay);
    // 2. qkv = h @ w_qkv
    hipLaunchKernelGGL(gemm_kernel, dim3(3 * D_DIM / TN, S_LEN / TM), dim3(256), 0, stream,
                       h_buf, w_qkv, (const float*)nullptr, qkv, S_LEN, 3 * D_DIM, D_DIM);
    // 3. split + qknorm + rope
    hipLaunchKernelGGL(split_rope_kernel, dim3(S_LEN, H_NUM), dim3(64), 0, stream,
                       qkv, q_norm_w, k_norm_w, qh, kh, vh);
    // 4. gamma gate
    hipLaunchKernelGGL(gamma_kernel, dim3(S_LEN), dim3(64), 0, stream,
                       h_buf, gamma_w1, gamma_w2, gammab);
    // 5. omega-rule memory (in-place q update)
    hipLaunchKernelGGL(omega_kernel, dim3(S_LEN, H_NUM), dim3(64), 0, stream,
                       qh, kh, gammab, decay, m_persist, mem_gate);
    // 6. causal attention -> ao (in qkv region; qkv dead after split)
    hipLaunchKernelGGL(attn_kernel, dim3(S_LEN, H_NUM), dim3(256), 0, stream,
                       qh, kh, vh, ao);
    // 7. x1 = x + ao @ w_o   (into d_out)
    hipLaunchKernelGGL(gemm_kernel, dim3(D_DIM / TN, S_LEN / TM), dim3(256), 0, stream,
                       ao, w_o, x, out, S_LEN, D_DIM, D_DIM);
    // 8. h2 = rms(x1, norm2_w)
    hipLaunchKernelGGL(rmsnorm_kernel, dim3(S_LEN), dim3(256), 0, stream, out, norm2_w, h_buf);
    // 9. G1 = h2 @ ffn_w1 ; G3 = h2 @ ffn_w3
    int ffn_bx = (FFN_H + TN - 1) / TN;
    hipLaunchKernelGGL(gemm_kernel, dim3(ffn_bx, S_LEN / TM), dim3(256), 0, stream,
                       h_buf, ffn_w1, (const float*)nullptr, G1, S_LEN, FFN_H, D_DIM);
    hipLaunchKernelGGL(gemm_kernel, dim3(ffn_bx, S_LEN / TM), dim3(256), 0, stream,
                       h_buf, ffn_w3, (const float*)nullptr, G3, S_LEN, FFN_H, D_DIM);
    // 10. mid = silu(G1) * G3  (in-place into G1)
    int nmid = S_LEN * FFN_H;
    hipLaunchKernelGGL(silumul_kernel, dim3((nmid + 255) / 256), dim3(256), 0, stream,
                       G1, G3, G1, nmid);
    // 11. out = x1 + mid @ ffn_w2
    hipLaunchKernelGGL(gemm_kernel, dim3(D_DIM / TN, S_LEN / TM), dim3(256), 0, stream,
                       G1, ffn_w2, out, out, S_LEN, D_DIM, FFN_H);
}

// Round 3
// 1452.152 us; speedup vs baseline: 2.3675x; 2.3675x over previous
//
#include <hip/hip_runtime.h>
#include <hip/hip_bf16.h>

#define S_LEN 2048
#define D_DIM 1024
#define H_NUM 16
#define HD_DIM 64
#define GH_DIM 64
#define FFN_H 2730
#define CTX_W 512
#define LAM 0.999f

typedef __attribute__((ext_vector_type(8))) short bf16x8_t;
typedef __attribute__((ext_vector_type(4))) float f32x4_t;

__device__ inline float wave_sum(float v) {
    for (int off = 32; off; off >>= 1) v += __shfl_xor(v, off);
    return v;
}

__device__ inline unsigned short f2bf(float f) {
    unsigned int u = __float_as_uint(f);
    unsigned int r = u + 0x7FFFu + ((u >> 16) & 1u);
    return (unsigned short)(r >> 16);
}

// ---------------- RMSNorm ---------------------------------------------------
__global__ __launch_bounds__(256) void rmsnorm_kernel(const float* __restrict__ in,
    const float* __restrict__ w, float* __restrict__ out)
{
    int row = blockIdx.x;
    const float4* ir = reinterpret_cast<const float4*>(in + (size_t)row * D_DIM);
    float4 v = ir[threadIdx.x];
    float ss = v.x*v.x + v.y*v.y + v.z*v.z + v.w*v.w;
    ss = wave_sum(ss);
    __shared__ float wsum[4];
    if ((threadIdx.x & 63) == 0) wsum[threadIdx.x >> 6] = ss;
    __syncthreads();
    float tot = wsum[0] + wsum[1] + wsum[2] + wsum[3];
    float scale = rsqrtf(tot / (float)D_DIM + 1e-6f);
    const float4* wr = reinterpret_cast<const float4*>(w);
    float4 wv = wr[threadIdx.x];
    float4 o;
    o.x = v.x * scale * wv.x; o.y = v.y * scale * wv.y;
    o.z = v.z * scale * wv.z; o.w = v.w * scale * wv.w;
    reinterpret_cast<float4*>(out + (size_t)row * D_DIM)[threadIdx.x] = o;
}

// ---------------- bf16 MFMA GEMM: C = [res +] A(MxK)@B(KxN), fp32 in/out ----
#define GBM 128
#define GBN 128
#define GBK 32
#define LDAK 40   // shorts per LDS row (32 data + 8 pad) = 80B, 16B-aligned rows
__global__ __launch_bounds__(256) void gemm_bf16_kernel(
    const float* __restrict__ A, const float* __restrict__ B,
    const float* __restrict__ res, float* __restrict__ C,
    int M, int N, int K)
{
    __shared__ unsigned short As[GBM][LDAK];
    __shared__ unsigned short Bs[GBN][LDAK];
    int tid = threadIdx.x;
    int lane = tid & 63;
    int wid  = tid >> 6;
    int wr = (wid >> 1) * 64;     // wave row offset within 128x128 tile
    int wc = (wid & 1) * 64;      // wave col offset
    int row0 = blockIdx.y * GBM;
    int col0 = blockIdx.x * GBN;
    f32x4_t acc[4][4];
    #pragma unroll
    for (int i = 0; i < 4; ++i)
        #pragma unroll
        for (int j = 0; j < 4; ++j) acc[i][j] = (f32x4_t)0.f;

    int ar = tid >> 3;            // 0..31 (A row group)
    int ak = (tid & 7) * 4;       // 0..28 (A k chunk)
    int bn = (tid >> 3) * 4;      // 0..124 (B col chunk)
    int bk = (tid & 7) * 4;       // 0..28  (B k chunk)

    for (int k0 = 0; k0 < K; k0 += GBK) {
        // stage A (rows always < M: M is a multiple of 128 here)
        #pragma unroll
        for (int p = 0; p < 4; ++p) {
            int r = ar + 32 * p;
            int gk = k0 + ak;
            const float* src = A + (size_t)(row0 + r) * K + gk;
            float4 v;
            if (gk + 3 < K) v = *(const float4*)src;
            else {
                v.x = (gk     < K) ? src[0] : 0.f;
                v.y = (gk + 1 < K) ? src[1] : 0.f;
                v.z = (gk + 2 < K) ? src[2] : 0.f;
                v.w = (gk + 3 < K) ? src[3] : 0.f;
            }
            ushort4 hq;
            hq.x = f2bf(v.x); hq.y = f2bf(v.y); hq.z = f2bf(v.z); hq.w = f2bf(v.w);
            *(ushort4*)&As[r][ak] = hq;
        }
        // stage B transposed: Bs[n][k] = B[k][n]
        {
            float rv[4][4];
            #pragma unroll
            for (int i = 0; i < 4; ++i) {
                int gk = k0 + bk + i;
                int gc = col0 + bn;
                if (gk < K && gc + 3 < N) {
                    float4 t4 = *(const float4*)(B + (size_t)gk * N + gc);
                    rv[i][0] = t4.x; rv[i][1] = t4.y; rv[i][2] = t4.z; rv[i][3] = t4.w;
                } else if (gk < K) {
                    const float* bp = B + (size_t)gk * N;
                    rv[i][0] = (gc     < N) ? bp[gc]     : 0.f;
                    rv[i][1] = (gc + 1 < N) ? bp[gc + 1] : 0.f;
                    rv[i][2] = (gc + 2 < N) ? bp[gc + 2] : 0.f;
                    rv[i][3] = (gc + 3 < N) ? bp[gc + 3] : 0.f;
                } else {
                    rv[i][0] = rv[i][1] = rv[i][2] = rv[i][3] = 0.f;
                }
            }
            #pragma unroll
            for (int j = 0; j < 4; ++j) {
                ushort4 hq;
                hq.x = f2bf(rv[0][j]); hq.y = f2bf(rv[1][j]);
                hq.z = f2bf(rv[2][j]); hq.w = f2bf(rv[3][j]);
                *(ushort4*)&Bs[bn + j][bk] = hq;
            }
        }
        __syncthreads();
        int fr = lane & 15;
        int fk = (lane >> 4) * 8;
        bf16x8_t af[4], bfr[4];
        #pragma unroll
        for (int mi = 0; mi < 4; ++mi)
            af[mi] = *(const bf16x8_t*)&As[wr + mi * 16 + fr][fk];
        #pragma unroll
        for (int ni = 0; ni < 4; ++ni)
            bfr[ni] = *(const bf16x8_t*)&Bs[wc + ni * 16 + fr][fk];
        #pragma unroll
        for (int mi = 0; mi < 4; ++mi)
            #pragma unroll
            for (int ni = 0; ni < 4; ++ni)
                acc[mi][ni] = __builtin_amdgcn_mfma_f32_16x16x32_bf16(
                    af[mi], bfr[ni], acc[mi][ni], 0, 0, 0);
        __syncthreads();
    }
    // epilogue: D row=(lane>>4)*4+j, col=lane&15 (HW-verified mapping)
    int dr = (lane >> 4) * 4;
    int dc = lane & 15;
    #pragma unroll
    for (int mi = 0; mi < 4; ++mi) {
        #pragma unroll
        for (int ni = 0; ni < 4; ++ni) {
            int gc = col0 + wc + ni * 16 + dc;
            if (gc >= N) continue;
            #pragma unroll
            for (int j = 0; j < 4; ++j) {
                int gr = row0 + wr + mi * 16 + dr + j;
                size_t off = (size_t)gr * N + gc;
                float v = acc[mi][ni][j];
                if (res) v += res[off];
                C[off] = v;
            }
        }
    }
}

// ------------- split qkv + qk rmsnorm + RoPE; layout (H, S, HD) ------------
__global__ __launch_bounds__(64) void split_rope_kernel(
    const float* __restrict__ qkv, const float* __restrict__ qw,
    const float* __restrict__ kw, float* __restrict__ qhp,
    float* __restrict__ khp, float* __restrict__ vhp)
{
    int s = blockIdx.x, h = blockIdx.y, d = threadIdx.x;
    size_t base = (size_t)s * (3 * D_DIM) + h * HD_DIM + d;
    float qv = qkv[base];
    float kv = qkv[base + D_DIM];
    float vv = qkv[base + 2 * D_DIM];
    float sq = wave_sum(qv * qv);
    float qn = qv * rsqrtf(sq / (float)HD_DIM + 1e-6f) * qw[d];
    float sk = wave_sum(kv * kv);
    float kn = kv * rsqrtf(sk / (float)HD_DIM + 1e-6f) * kw[d];
    int j = d & 31;
    float inv = expf(-(float)j * (9.2103403719761836f / 32.0f)); // 10000^(-j/32)
    float ang = (float)s * inv;
    float cs = cosf(ang), sn = sinf(ang);
    float qp = __shfl_xor(qn, 32);
    float kp = __shfl_xor(kn, 32);
    float sgn = (d < 32) ? -1.f : 1.f;
    float qo = qn * cs + sgn * qp * sn;
    float ko = kn * cs + sgn * kp * sn;
    size_t ob = ((size_t)h * S_LEN + s) * HD_DIM + d;
    qhp[ob] = qo; khp[ob] = ko; vhp[ob] = vv;
}

// ------------- gamma gate ---------------------------------------------------
__global__ __launch_bounds__(64) void gamma_kernel(const float* __restrict__ h,
    const float* __restrict__ w1, const float* __restrict__ w2,
    float* __restrict__ gamma)
{
    __shared__ float hl[D_DIM];
    int s = blockIdx.x, j = threadIdx.x;
    for (int k = j; k < D_DIM; k += 64) hl[k] = h[(size_t)s * D_DIM + k];
    __syncthreads();
    float acc = 0.f;
    for (int k = 0; k < D_DIM; ++k) acc += hl[k] * w1[k * GH_DIM + j];
    float z = acc / (1.f + __expf(-acc));
    float y = z * w2[j];
    float tot = wave_sum(y);
    if (j == 0) gamma[s] = 1.f / (1.f + __expf(-tot));
}

__global__ void fill_decay_kernel(float* __restrict__ decay) {
    int i = threadIdx.x;
    if (i < CTX_W) decay[i] = powf(LAM, (float)i);
}

// ------------- omega-rule memory, tiled (in-place q update) ----------------
#define QBLK 64
#define KBLK 64
__global__ __launch_bounds__(256) void omega_flash_kernel(
    float* __restrict__ qhp, const float* __restrict__ khp,
    const float* __restrict__ gamma, const float* __restrict__ decay,
    const float* __restrict__ mp, const float* __restrict__ mg)
{
    __shared__ float Ks[KBLK][68];
    __shared__ float Qs[QBLK][68];
    __shared__ float Ds[CTX_W];
    __shared__ float Gs[KBLK];
    int tid = threadIdx.x;
    int r = tid >> 2, g = tid & 3;
    int h = blockIdx.y, qt = blockIdx.x;
    int q0 = qt * QBLK;
    int t = q0 + r;
    for (int i = tid; i < CTX_W; i += 256) Ds[i] = decay[i];
    float4 qv[4];
    #pragma unroll
    for (int jj = 0; jj < 4; ++jj) {
        qv[jj] = *(const float4*)(qhp + ((size_t)h * S_LEN + t) * HD_DIM + g * 16 + jj * 4);
        *(float4*)&Qs[r][g * 16 + jj * 4] = qv[jj];
    }
    float o[16];
    #pragma unroll
    for (int j = 0; j < 16; ++j) o[j] = 0.f;
    float wsum = 0.f;
    int kt0 = 0;
    if (q0 - (CTX_W - 1) > 0) kt0 = (q0 - (CTX_W - 1)) >> 6;
    for (int kt = kt0; kt <= qt; ++kt) {
        int k0 = kt * KBLK;
        #pragma unroll
        for (int p = 0; p < 4; ++p) {
            int idx = tid + p * 256;
            int c = idx >> 4, dd = (idx & 15) * 4;
            *(float4*)&Ks[c][dd] =
                *(const float4*)(khp + ((size_t)h * S_LEN + k0 + c) * HD_DIM + dd);
        }
        if (tid < KBLK) Gs[tid] = gamma[k0 + tid];
        __syncthreads();
        for (int c = 0; c < KBLK; ++c) {
            float4 k4[4];
            float s = 0.f;
            #pragma unroll
            for (int jj = 0; jj < 4; ++jj) {
                k4[jj] = *(const float4*)&Ks[c][g * 16 + jj * 4];
                s += qv[jj].x * k4[jj].x + qv[jj].y * k4[jj].y +
                     qv[jj].z * k4[jj].z + qv[jj].w * k4[jj].w;
            }
            s += __shfl_xor(s, 1);
            s += __shfl_xor(s, 2);
            int delta = t - (k0 + c);
            float w = 0.f;
            if (delta >= 0 && delta < CTX_W) w = Ds[delta] * Gs[c];
            wsum += w;
            float ws = w * s;
            #pragma unroll
            for (int jj = 0; jj < 4; ++jj) {
                o[jj * 4 + 0] += ws * k4[jj].x;
                o[jj * 4 + 1] += ws * k4[jj].y;
                o[jj * 4 + 2] += ws * k4[jj].z;
                o[jj * 4 + 3] += ws * k4[jj].w;
            }
        }
        __syncthreads();
    }
    float gate = 1.f / (1.f + __expf(-mg[0]));
    float keep = 1.f - gate;
    float invn = gate / (1.f + wsum);
    const float* mph = mp + (size_t)h * HD_DIM * HD_DIM;
    #pragma unroll
    for (int jj = 0; jj < 4; ++jj) {
        float ov[4];
        #pragma unroll
        for (int q4 = 0; q4 < 4; ++q4) {
            int d = g * 16 + jj * 4 + q4;
            const float* mrow = mph + (size_t)d * HD_DIM;
            float pd = 0.f;
            #pragma unroll 8
            for (int e = 0; e < HD_DIM; ++e) pd += mrow[e] * Qs[r][e];
            float qold = (q4 == 0) ? qv[jj].x : (q4 == 1) ? qv[jj].y
                       : (q4 == 2) ? qv[jj].z : qv[jj].w;
            ov[q4] = keep * qold + invn * (pd + o[jj * 4 + q4]);
        }
        float4 wv4 = make_float4(ov[0], ov[1], ov[2], ov[3]);
        *(float4*)(qhp + ((size_t)h * S_LEN + t) * HD_DIM + g * 16 + jj * 4) = wv4;
    }
}

// ------------- flash attention, one block per (head, 64-query tile) --------
__global__ __launch_bounds__(256) void attn_flash_kernel(
    const float* __restrict__ qhp, const float* __restrict__ khp,
    const float* __restrict__ vhp, float* __restrict__ ao)
{
    __shared__ float Ks[KBLK][68];
    __shared__ float Vs[KBLK][68];
    __shared__ float Ps[QBLK][68];
    int tid = threadIdx.x;
    int r = tid >> 2, g = tid & 3;
    int h = blockIdx.y, qt = blockIdx.x;
    int q0 = qt * QBLK;
    int t = q0 + r;
    float4 qv[4];
    #pragma unroll
    for (int jj = 0; jj < 4; ++jj)
        qv[jj] = *(const float4*)(qhp + ((size_t)h * S_LEN + t) * HD_DIM + g * 16 + jj * 4);
    float o[16];
    #pragma unroll
    for (int j = 0; j < 16; ++j) o[j] = 0.f;
    float m = -1e30f, l = 0.f;
    for (int kt = 0; kt <= qt; ++kt) {
        int k0 = kt * KBLK;
        #pragma unroll
        for (int p = 0; p < 4; ++p) {
            int idx = tid + p * 256;
            int c = idx >> 4, dd = (idx & 15) * 4;
            *(float4*)&Ks[c][dd] =
                *(const float4*)(khp + ((size_t)h * S_LEN + k0 + c) * HD_DIM + dd);
            *(float4*)&Vs[c][dd] =
                *(const float4*)(vhp + ((size_t)h * S_LEN + k0 + c) * HD_DIM + dd);
        }
        __syncthreads();
        float tmax = -1e30f;
        bool diag = (kt == qt);
        for (int c = 0; c < KBLK; ++c) {
            float s = 0.f;
            #pragma unroll
            for (int jj = 0; jj < 4; ++jj) {
                float4 kk4 = *(const float4*)&Ks[c][g * 16 + jj * 4];
                s += qv[jj].x * kk4.x + qv[jj].y * kk4.y +
                     qv[jj].z * kk4.z + qv[jj].w * kk4.w;
            }
            s += __shfl_xor(s, 1);
            s += __shfl_xor(s, 2);
            s *= 0.125f;
            if (diag && (k0 + c > t)) s = -1e30f;
            if (g == 0) Ps[r][c] = s;
            tmax = fmaxf(tmax, s);
        }
        __syncthreads();
        float mnew = fmaxf(m, tmax);
        float corr = __expf(m - mnew);
        l *= corr;
        #pragma unroll
        for (int j = 0; j < 16; ++j) o[j] *= corr;
        m = mnew;
        for (int c = 0; c < KBLK; ++c) {
            float p = __expf(Ps[r][c] - m);
            l += p;
            #pragma unroll
            for (int jj = 0; jj < 4; ++jj) {
                float4 vv4 = *(const float4*)&Vs[c][g * 16 + jj * 4];
                o[jj * 4 + 0] += p * vv4.x;
                o[jj * 4 + 1] += p * vv4.y;
                o[jj * 4 + 2] += p * vv4.z;
                o[jj * 4 + 3] += p * vv4.w;
            }
        }
        __syncthreads();
    }
    float inv = 1.f / l;
    #pragma unroll
    for (int jj = 0; jj < 4; ++jj) {
        float4 ov;
        ov.x = o[jj * 4 + 0] * inv; ov.y = o[jj * 4 + 1] * inv;
        ov.z = o[jj * 4 + 2] * inv; ov.w = o[jj * 4 + 3] * inv;
        *(float4*)(ao + (size_t)t * D_DIM + h * HD_DIM + g * 16 + jj * 4) = ov;
    }
}

// ------------- SwiGLU elementwise ------------------------------------------
__global__ void silumul_kernel(const float* __restrict__ g1,
    const float* __restrict__ g3, float* __restrict__ out, int n)
{
    int i = blockIdx.x * blockDim.x + threadIdx.x;
    if (i < n) {
        float a = g1[i];
        out[i] = a / (1.f + __expf(-a)) * g3[i];
    }
}

extern "C" void kernel_launch(void* const* d_in, const int* in_sizes, int n_in,
                              void* d_out, int out_size, void* d_ws, size_t ws_size,
                              hipStream_t stream) {
    const float* x         = (const float*)d_in[0];
    const float* norm1_w   = (const float*)d_in[1];
    const float* norm2_w   = (const float*)d_in[2];
    const float* w_qkv     = (const float*)d_in[3];
    const float* q_norm_w  = (const float*)d_in[4];
    const float* k_norm_w  = (const float*)d_in[5];
    const float* gamma_w1  = (const float*)d_in[6];
    const float* gamma_w2  = (const float*)d_in[7];
    const float* m_persist = (const float*)d_in[8];
    const float* mem_gate  = (const float*)d_in[9];
    const float* w_o       = (const float*)d_in[10];
    const float* ffn_w1    = (const float*)d_in[11];
    const float* ffn_w3    = (const float*)d_in[12];
    const float* ffn_w2    = (const float*)d_in[13];
    float* out = (float*)d_out;
    char* ws = (char*)d_ws;

    const size_t MB = 1024 * 1024;
    float* h_buf  = (float*)(ws);            // [0,  8MB): h, later h2
    float* qkv    = (float*)(ws + 8  * MB);  // [8, 32MB): qkv; later ao; later G1
    float* qh     = (float*)(ws + 32 * MB);  // [32,40MB): q (H,S,HD)
    float* kh     = (float*)(ws + 40 * MB);  // [40,48MB): k (H,S,HD)
    float* vh     = (float*)(ws + 48 * MB);  // [48,56MB): v (H,S,HD)
    float* gammab = (float*)(ws + 56 * MB);  // 8KB gamma per token
    float* decay  = gammab + S_LEN;          // 2KB lambda^delta table
    float* ao = qkv;   // qkv dead after split_rope
    float* G1 = qkv;   // ao dead after w_o gemm; 22.4MB fits in 24MB region
    float* G3 = qh;    // q/k/v dead after attention; spans qh/kh/vh region

    // 1. h = rms(x, norm1_w)
    hipLaunchKernelGGL(rmsnorm_kernel, dim3(S_LEN), dim3(256), 0, stream, x, norm1_w, h_buf);
    hipLaunchKernelGGL(fill_decay_kernel, dim3(1), dim3(512), 0, stream, decay);
    // 2. qkv = h @ w_qkv
    hipLaunchKernelGGL(gemm_bf16_kernel, dim3(3 * D_DIM / GBN, S_LEN / GBM), dim3(256), 0, stream,
                       h_buf, w_qkv, (const float*)nullptr, qkv, S_LEN, 3 * D_DIM, D_DIM);
    // 3. split + qknorm + rope
    hipLaunchKernelGGL(split_rope_kernel, dim3(S_LEN, H_NUM), dim3(64), 0, stream,
                       qkv, q_norm_w, k_norm_w, qh, kh, vh);
    // 4. gamma gate
    hipLaunchKernelGGL(gamma_kernel, dim3(S_LEN), dim3(64), 0, stream,
                       h_buf, gamma_w1, gamma_w2, gammab);
    // 5. omega-rule memory (in-place q update)
    hipLaunchKernelGGL(omega_flash_kernel, dim3(S_LEN / QBLK, H_NUM), dim3(256), 0, stream,
                       qh, kh, gammab, decay, m_persist, mem_gate);
    // 6. causal attention -> ao
    hipLaunchKernelGGL(attn_flash_kernel, dim3(S_LEN / QBLK, H_NUM), dim3(256), 0, stream,
                       qh, kh, vh, ao);
    // 7. x1 = x + ao @ w_o   (into d_out)
    hipLaunchKernelGGL(gemm_bf16_kernel, dim3(D_DIM / GBN, S_LEN / GBM), dim3(256), 0, stream,
                       ao, w_o, x, out, S_LEN, D_DIM, D_DIM);
    // 8. h2 = rms(x1, norm2_w)
    hipLaunchKernelGGL(rmsnorm_kernel, dim3(S_LEN), dim3(256), 0, stream, out, norm2_w, h_buf);
    // 9. G1 = h2 @ ffn_w1 ; G3 = h2 @ ffn_w3
    int ffn_bx = (FFN_H + GBN - 1) / GBN;
    hipLaunchKernelGGL(gemm_bf16_kernel, dim3(ffn_bx, S_LEN / GBM), dim3(256), 0, stream,
                       h_buf, ffn_w1, (const float*)nullptr, G1, S_LEN, FFN_H, D_DIM);
    hipLaunchKernelGGL(gemm_bf16_kernel, dim3(ffn_bx, S_LEN / GBM), dim3(256), 0, stream,
                       h_buf, ffn_w3, (const float*)nullptr, G3, S_LEN, FFN_H, D_DIM);
    // 10. mid = silu(G1) * G3  (in-place into G1)
    int nmid = S_LEN * FFN_H;
    hipLaunchKernelGGL(silumul_kernel, dim3((nmid + 255) / 256), dim3(256), 0, stream,
                       G1, G3, G1, nmid);
    // 11. out = x1 + mid @ ffn_w2
    hipLaunchKernelGGL(gemm_bf16_kernel, dim3(D_DIM / GBN, S_LEN / GBM), dim3(256), 0, stream,
                       G1, ffn_w2, out, out, S_LEN, D_DIM, FFN_H);
}

// Round 4
// 844.137 us; speedup vs baseline: 4.0727x; 1.7203x over previous
//
#include <hip/hip_runtime.h>
#include <hip/hip_bf16.h>

#define S_LEN 2048
#define D_DIM 1024
#define H_NUM 16
#define HD_DIM 64
#define GH_DIM 64
#define FFN_H 2730
#define CTX_W 512
#define LAM 0.999f

typedef __attribute__((ext_vector_type(8))) short bf16x8_t;
typedef __attribute__((ext_vector_type(4))) float f32x4_t;

__device__ inline float wave_sum(float v) {
    for (int off = 32; off; off >>= 1) v += __shfl_xor(v, off);
    return v;
}

__device__ inline unsigned short f2bf(float f) {
    unsigned int u = __float_as_uint(f);
    unsigned int r = u + 0x7FFFu + ((u >> 16) & 1u);
    return (unsigned short)(r >> 16);
}

// ---------------- RMSNorm ---------------------------------------------------
__global__ __launch_bounds__(256) void rmsnorm_kernel(const float* __restrict__ in,
    const float* __restrict__ w, float* __restrict__ out)
{
    int row = blockIdx.x;
    const float4* ir = reinterpret_cast<const float4*>(in + (size_t)row * D_DIM);
    float4 v = ir[threadIdx.x];
    float ss = v.x*v.x + v.y*v.y + v.z*v.z + v.w*v.w;
    ss = wave_sum(ss);
    __shared__ float wsum[4];
    if ((threadIdx.x & 63) == 0) wsum[threadIdx.x >> 6] = ss;
    __syncthreads();
    float tot = wsum[0] + wsum[1] + wsum[2] + wsum[3];
    float scale = rsqrtf(tot / (float)D_DIM + 1e-6f);
    const float4* wr = reinterpret_cast<const float4*>(w);
    float4 wv = wr[threadIdx.x];
    float4 o;
    o.x = v.x * scale * wv.x; o.y = v.y * scale * wv.y;
    o.z = v.z * scale * wv.z; o.w = v.w * scale * wv.w;
    reinterpret_cast<float4*>(out + (size_t)row * D_DIM)[threadIdx.x] = o;
}

// ---------------- bf16 MFMA GEMM: C = [res +] A(MxK)@B(KxN), fp32 in/out ----
#define GBM 128
#define GBN 128
#define GBK 32
#define LDAK 40
__global__ __launch_bounds__(256) void gemm_bf16_kernel(
    const float* __restrict__ A, const float* __restrict__ B,
    const float* __restrict__ res, float* __restrict__ C,
    int M, int N, int K)
{
    __shared__ unsigned short As[GBM][LDAK];
    __shared__ unsigned short Bs[GBN][LDAK];
    int tid = threadIdx.x;
    int lane = tid & 63;
    int wid  = tid >> 6;
    int wr = (wid >> 1) * 64;
    int wc = (wid & 1) * 64;
    int row0 = blockIdx.y * GBM;
    int col0 = blockIdx.x * GBN;
    f32x4_t acc[4][4];
    #pragma unroll
    for (int i = 0; i < 4; ++i)
        #pragma unroll
        for (int j = 0; j < 4; ++j) acc[i][j] = (f32x4_t)0.f;

    int ar = tid >> 3;
    int ak = (tid & 7) * 4;
    int bn = (tid >> 3) * 4;
    int bk = (tid & 7) * 4;

    for (int k0 = 0; k0 < K; k0 += GBK) {
        #pragma unroll
        for (int p = 0; p < 4; ++p) {
            int r = ar + 32 * p;
            int gk = k0 + ak;
            const float* src = A + (size_t)(row0 + r) * K + gk;
            float4 v;
            if (gk + 3 < K) v = *(const float4*)src;
            else {
                v.x = (gk     < K) ? src[0] : 0.f;
                v.y = (gk + 1 < K) ? src[1] : 0.f;
                v.z = (gk + 2 < K) ? src[2] : 0.f;
                v.w = (gk + 3 < K) ? src[3] : 0.f;
            }
            ushort4 hq;
            hq.x = f2bf(v.x); hq.y = f2bf(v.y); hq.z = f2bf(v.z); hq.w = f2bf(v.w);
            *(ushort4*)&As[r][ak] = hq;
        }
        {
            float rv[4][4];
            #pragma unroll
            for (int i = 0; i < 4; ++i) {
                int gk = k0 + bk + i;
                int gc = col0 + bn;
                if (gk < K && gc + 3 < N) {
                    float4 t4 = *(const float4*)(B + (size_t)gk * N + gc);
                    rv[i][0] = t4.x; rv[i][1] = t4.y; rv[i][2] = t4.z; rv[i][3] = t4.w;
                } else if (gk < K) {
                    const float* bp = B + (size_t)gk * N;
                    rv[i][0] = (gc     < N) ? bp[gc]     : 0.f;
                    rv[i][1] = (gc + 1 < N) ? bp[gc + 1] : 0.f;
                    rv[i][2] = (gc + 2 < N) ? bp[gc + 2] : 0.f;
                    rv[i][3] = (gc + 3 < N) ? bp[gc + 3] : 0.f;
                } else {
                    rv[i][0] = rv[i][1] = rv[i][2] = rv[i][3] = 0.f;
                }
            }
            #pragma unroll
            for (int j = 0; j < 4; ++j) {
                ushort4 hq;
                hq.x = f2bf(rv[0][j]); hq.y = f2bf(rv[1][j]);
                hq.z = f2bf(rv[2][j]); hq.w = f2bf(rv[3][j]);
                *(ushort4*)&Bs[bn + j][bk] = hq;
            }
        }
        __syncthreads();
        int fr = lane & 15;
        int fk = (lane >> 4) * 8;
        bf16x8_t af[4], bfr[4];
        #pragma unroll
        for (int mi = 0; mi < 4; ++mi)
            af[mi] = *(const bf16x8_t*)&As[wr + mi * 16 + fr][fk];
        #pragma unroll
        for (int ni = 0; ni < 4; ++ni)
            bfr[ni] = *(const bf16x8_t*)&Bs[wc + ni * 16 + fr][fk];
        #pragma unroll
        for (int mi = 0; mi < 4; ++mi)
            #pragma unroll
            for (int ni = 0; ni < 4; ++ni)
                acc[mi][ni] = __builtin_amdgcn_mfma_f32_16x16x32_bf16(
                    af[mi], bfr[ni], acc[mi][ni], 0, 0, 0);
        __syncthreads();
    }
    int dr = (lane >> 4) * 4;
    int dc = lane & 15;
    #pragma unroll
    for (int mi = 0; mi < 4; ++mi) {
        #pragma unroll
        for (int ni = 0; ni < 4; ++ni) {
            int gc = col0 + wc + ni * 16 + dc;
            if (gc >= N) continue;
            #pragma unroll
            for (int j = 0; j < 4; ++j) {
                int gr = row0 + wr + mi * 16 + dr + j;
                size_t off = (size_t)gr * N + gc;
                float v = acc[mi][ni][j];
                if (res) v += res[off];
                C[off] = v;
            }
        }
    }
}

// ------------- split qkv + qk rmsnorm + RoPE; layout (H, S, HD) ------------
__global__ __launch_bounds__(64) void split_rope_kernel(
    const float* __restrict__ qkv, const float* __restrict__ qw,
    const float* __restrict__ kw, float* __restrict__ qhp,
    float* __restrict__ khp, float* __restrict__ vhp)
{
    int s = blockIdx.x, h = blockIdx.y, d = threadIdx.x;
    size_t base = (size_t)s * (3 * D_DIM) + h * HD_DIM + d;
    float qv = qkv[base];
    float kv = qkv[base + D_DIM];
    float vv = qkv[base + 2 * D_DIM];
    float sq = wave_sum(qv * qv);
    float qn = qv * rsqrtf(sq / (float)HD_DIM + 1e-6f) * qw[d];
    float sk = wave_sum(kv * kv);
    float kn = kv * rsqrtf(sk / (float)HD_DIM + 1e-6f) * kw[d];
    int j = d & 31;
    float inv = expf(-(float)j * (9.2103403719761836f / 32.0f));
    float ang = (float)s * inv;
    float cs = cosf(ang), sn = sinf(ang);
    float qp = __shfl_xor(qn, 32);
    float kp = __shfl_xor(kn, 32);
    float sgn = (d < 32) ? -1.f : 1.f;
    float qo = qn * cs + sgn * qp * sn;
    float ko = kn * cs + sgn * kp * sn;
    size_t ob = ((size_t)h * S_LEN + s) * HD_DIM + d;
    qhp[ob] = qo; khp[ob] = ko; vhp[ob] = vv;
}

// ------------- gamma gate ---------------------------------------------------
__global__ __launch_bounds__(64) void gamma_kernel(const float* __restrict__ h,
    const float* __restrict__ w1, const float* __restrict__ w2,
    float* __restrict__ gamma)
{
    __shared__ float hl[D_DIM];
    int s = blockIdx.x, j = threadIdx.x;
    for (int k = j; k < D_DIM; k += 64) hl[k] = h[(size_t)s * D_DIM + k];
    __syncthreads();
    float acc = 0.f;
    for (int k = 0; k < D_DIM; ++k) acc += hl[k] * w1[k * GH_DIM + j];
    float z = acc / (1.f + __expf(-acc));
    float y = z * w2[j];
    float tot = wave_sum(y);
    if (j == 0) gamma[s] = 1.f / (1.f + __expf(-tot));
}

// ============ MFMA omega-rule: in-place q update ============================
#define QBLK 64
#define KBLK 64
#define ALDK 72   // shorts per LDS row: 144B, 16B aligned, stride 36 banks
#define L2LAM -0.00144341687f   // log2(0.999)

__global__ __launch_bounds__(256) void omega_mfma_kernel(
    float* __restrict__ qhp, const float* __restrict__ khp,
    const float* __restrict__ gammab, const float* __restrict__ mp,
    const float* __restrict__ mg)
{
    __shared__ unsigned short Ks[KBLK][ALDK];
    __shared__ unsigned short Kt[HD_DIM][ALDK];
    __shared__ unsigned short Ps[QBLK][ALDK];
    int tid = threadIdx.x, lane = tid & 63, wq = tid >> 6;
    int h = blockIdx.y;
    int qt = (h & 8) ? ((int)gridDim.x - 1 - blockIdx.x) : blockIdx.x;
    int q0 = qt * QBLK;
    int fr = lane & 15, fko = (lane >> 4) * 8;
    int c = lane & 15, rg = lane >> 4;
    int rowt[4];
    float rowf[4];
    #pragma unroll
    for (int j = 0; j < 4; ++j) {
        rowt[j] = q0 + wq * 16 + rg * 4 + j;
        rowf[j] = exp2f((float)(wq * 16 + rg * 4 + j) * L2LAM);
    }
    // Q fragments (original q, reused for scores and persist)
    bf16x8_t qf[2];
    {
        const float* qrow = qhp + ((size_t)h * S_LEN + q0 + wq * 16 + fr) * HD_DIM;
        #pragma unroll
        for (int kh = 0; kh < 2; ++kh) {
            float4 a = *(const float4*)(qrow + kh * 32 + fko);
            float4 b = *(const float4*)(qrow + kh * 32 + fko + 4);
            bf16x8_t f;
            f[0]=f2bf(a.x); f[1]=f2bf(a.y); f[2]=f2bf(a.z); f[3]=f2bf(a.w);
            f[4]=f2bf(b.x); f[5]=f2bf(b.y); f[6]=f2bf(b.z); f[7]=f2bf(b.w);
            qf[kh] = f;
        }
    }
    f32x4_t accc[4];
    #pragma unroll
    for (int n = 0; n < 4; ++n) accc[n] = (f32x4_t)0.f;
    float wsum[4] = {0.f, 0.f, 0.f, 0.f};
    int kt0 = 0;
    if (q0 - (CTX_W - 1) > 0) kt0 = (q0 - (CTX_W - 1)) / KBLK;
    int si = tid >> 2, sdb = (tid & 3) * 16;
    for (int kt = kt0; kt <= qt; ++kt) {
        int k0 = kt * KBLK;
        {   // stage K rows (bf16) + K transposed
            union { unsigned short u[16]; bf16x8_t v[2]; } kq;
            const float* kr = khp + ((size_t)h * S_LEN + k0 + si) * HD_DIM + sdb;
            #pragma unroll
            for (int e4 = 0; e4 < 4; ++e4) {
                float4 t4 = *(const float4*)(kr + e4 * 4);
                kq.u[e4*4+0] = f2bf(t4.x); kq.u[e4*4+1] = f2bf(t4.y);
                kq.u[e4*4+2] = f2bf(t4.z); kq.u[e4*4+3] = f2bf(t4.w);
            }
            *(bf16x8_t*)&Ks[si][sdb]     = kq.v[0];
            *(bf16x8_t*)&Ks[si][sdb + 8] = kq.v[1];
            #pragma unroll
            for (int e = 0; e < 16; ++e) Kt[sdb + e][si] = kq.u[e];
        }
        __syncthreads();
        f32x4_t s[4];
        #pragma unroll
        for (int n = 0; n < 4; ++n) s[n] = (f32x4_t)0.f;
        #pragma unroll
        for (int kh = 0; kh < 2; ++kh) {
            #pragma unroll
            for (int n = 0; n < 4; ++n) {
                bf16x8_t kb = *(const bf16x8_t*)&Ks[n * 16 + fr][kh * 32 + fko];
                s[n] = __builtin_amdgcn_mfma_f32_16x16x32_bf16(qf[kh], kb, s[n], 0, 0, 0);
            }
        }
        // weights w = lambda^(t-i)*gamma[i] (window-masked), P = w*s -> LDS bf16
        #pragma unroll
        for (int n = 0; n < 4; ++n) {
            int icol = k0 + n * 16 + c;
            float colf = exp2f((float)(q0 - icol) * L2LAM) * gammab[icol];
            #pragma unroll
            for (int j = 0; j < 4; ++j) {
                int delta = rowt[j] - icol;
                float w = (delta >= 0 && delta < CTX_W) ? rowf[j] * colf : 0.f;
                wsum[j] += w;
                Ps[wq * 16 + rg * 4 + j][n * 16 + c] = f2bf(w * s[n][j]);
            }
        }
        // contrib += P @ K  (B-operand = K^T rows)
        #pragma unroll
        for (int kh = 0; kh < 2; ++kh) {
            bf16x8_t pa = *(const bf16x8_t*)&Ps[wq * 16 + fr][kh * 32 + fko];
            #pragma unroll
            for (int n = 0; n < 4; ++n) {
                bf16x8_t kb = *(const bf16x8_t*)&Kt[n * 16 + fr][kh * 32 + fko];
                accc[n] = __builtin_amdgcn_mfma_f32_16x16x32_bf16(pa, kb, accc[n], 0, 0, 0);
            }
        }
        __syncthreads();
    }
    // persist = q @ M_p^T  (B-operand rows = m_persist[h][d][:], contiguous)
    f32x4_t pacc[4];
    #pragma unroll
    for (int n = 0; n < 4; ++n) pacc[n] = (f32x4_t)0.f;
    const float* mph = mp + (size_t)h * HD_DIM * HD_DIM;
    #pragma unroll
    for (int kh = 0; kh < 2; ++kh) {
        #pragma unroll
        for (int n = 0; n < 4; ++n) {
            const float* br = mph + (size_t)(n * 16 + fr) * HD_DIM + kh * 32 + fko;
            float4 a = *(const float4*)br;
            float4 b = *(const float4*)(br + 4);
            bf16x8_t f;
            f[0]=f2bf(a.x); f[1]=f2bf(a.y); f[2]=f2bf(a.z); f[3]=f2bf(a.w);
            f[4]=f2bf(b.x); f[5]=f2bf(b.y); f[6]=f2bf(b.z); f[7]=f2bf(b.w);
            pacc[n] = __builtin_amdgcn_mfma_f32_16x16x32_bf16(qf[kh], f, pacc[n], 0, 0, 0);
        }
    }
    #pragma unroll
    for (int j = 0; j < 4; ++j) {
        wsum[j] += __shfl_xor(wsum[j], 1);
        wsum[j] += __shfl_xor(wsum[j], 2);
        wsum[j] += __shfl_xor(wsum[j], 4);
        wsum[j] += __shfl_xor(wsum[j], 8);
    }
    float gate = 1.f / (1.f + __expf(-mg[0]));
    float keep = 1.f - gate;
    #pragma unroll
    for (int n = 0; n < 4; ++n) {
        #pragma unroll
        for (int j = 0; j < 4; ++j) {
            size_t off = ((size_t)h * S_LEN + rowt[j]) * HD_DIM + n * 16 + c;
            float qold = qhp[off];
            qhp[off] = keep * qold +
                       gate * (pacc[n][j] + accc[n][j]) / (1.f + wsum[j]);
        }
    }
}

// ============ MFMA flash attention ==========================================
__global__ __launch_bounds__(256) void attn_mfma_kernel(
    const float* __restrict__ qhp, const float* __restrict__ khp,
    const float* __restrict__ vhp, float* __restrict__ ao)
{
    __shared__ unsigned short Ks[KBLK][ALDK];
    __shared__ unsigned short Vt[HD_DIM][ALDK];
    __shared__ unsigned short Ps[QBLK][ALDK];
    int tid = threadIdx.x, lane = tid & 63, wq = tid >> 6;
    int h = blockIdx.y;
    int qt = (h & 8) ? ((int)gridDim.x - 1 - blockIdx.x) : blockIdx.x;
    int q0 = qt * QBLK;
    int fr = lane & 15, fko = (lane >> 4) * 8;
    int c = lane & 15, rg = lane >> 4;
    int rowt[4];
    #pragma unroll
    for (int j = 0; j < 4; ++j) rowt[j] = q0 + wq * 16 + rg * 4 + j;
    bf16x8_t qf[2];
    {
        const float* qrow = qhp + ((size_t)h * S_LEN + q0 + wq * 16 + fr) * HD_DIM;
        #pragma unroll
        for (int kh = 0; kh < 2; ++kh) {
            float4 a = *(const float4*)(qrow + kh * 32 + fko);
            float4 b = *(const float4*)(qrow + kh * 32 + fko + 4);
            bf16x8_t f;
            f[0]=f2bf(a.x); f[1]=f2bf(a.y); f[2]=f2bf(a.z); f[3]=f2bf(a.w);
            f[4]=f2bf(b.x); f[5]=f2bf(b.y); f[6]=f2bf(b.z); f[7]=f2bf(b.w);
            qf[kh] = f;
        }
    }
    f32x4_t acco[4];
    #pragma unroll
    for (int n = 0; n < 4; ++n) acco[n] = (f32x4_t)0.f;
    float m_run[4] = {-1e30f, -1e30f, -1e30f, -1e30f};
    float l_run[4] = {0.f, 0.f, 0.f, 0.f};
    int si = tid >> 2, sdb = (tid & 3) * 16;
    for (int kt = 0; kt <= qt; ++kt) {
        int k0 = kt * KBLK;
        {   // stage K rows (bf16) + V transposed (bf16)
            union { unsigned short u[16]; bf16x8_t v[2]; } kq, vq;
            const float* kr = khp + ((size_t)h * S_LEN + k0 + si) * HD_DIM + sdb;
            const float* vr = vhp + ((size_t)h * S_LEN + k0 + si) * HD_DIM + sdb;
            #pragma unroll
            for (int e4 = 0; e4 < 4; ++e4) {
                float4 t4 = *(const float4*)(kr + e4 * 4);
                float4 u4 = *(const float4*)(vr + e4 * 4);
                kq.u[e4*4+0] = f2bf(t4.x); kq.u[e4*4+1] = f2bf(t4.y);
                kq.u[e4*4+2] = f2bf(t4.z); kq.u[e4*4+3] = f2bf(t4.w);
                vq.u[e4*4+0] = f2bf(u4.x); vq.u[e4*4+1] = f2bf(u4.y);
                vq.u[e4*4+2] = f2bf(u4.z); vq.u[e4*4+3] = f2bf(u4.w);
            }
            *(bf16x8_t*)&Ks[si][sdb]     = kq.v[0];
            *(bf16x8_t*)&Ks[si][sdb + 8] = kq.v[1];
            #pragma unroll
            for (int e = 0; e < 16; ++e) Vt[sdb + e][si] = vq.u[e];
        }
        __syncthreads();
        f32x4_t s[4];
        #pragma unroll
        for (int n = 0; n < 4; ++n) s[n] = (f32x4_t)0.f;
        #pragma unroll
        for (int kh = 0; kh < 2; ++kh) {
            #pragma unroll
            for (int n = 0; n < 4; ++n) {
                bf16x8_t kb = *(const bf16x8_t*)&Ks[n * 16 + fr][kh * 32 + fko];
                s[n] = __builtin_amdgcn_mfma_f32_16x16x32_bf16(qf[kh], kb, s[n], 0, 0, 0);
            }
        }
        float tmax[4] = {-1e30f, -1e30f, -1e30f, -1e30f};
        #pragma unroll
        for (int n = 0; n < 4; ++n) {
            int icol = k0 + n * 16 + c;
            #pragma unroll
            for (int j = 0; j < 4; ++j) {
                float v = s[n][j] * 0.125f;
                if (icol > rowt[j]) v = -1e30f;
                s[n][j] = v;
                tmax[j] = fmaxf(tmax[j], v);
            }
        }
        #pragma unroll
        for (int j = 0; j < 4; ++j) {
            tmax[j] = fmaxf(tmax[j], __shfl_xor(tmax[j], 1));
            tmax[j] = fmaxf(tmax[j], __shfl_xor(tmax[j], 2));
            tmax[j] = fmaxf(tmax[j], __shfl_xor(tmax[j], 4));
            tmax[j] = fmaxf(tmax[j], __shfl_xor(tmax[j], 8));
        }
        float corr[4];
        #pragma unroll
        for (int j = 0; j < 4; ++j) {
            float mn = fmaxf(m_run[j], tmax[j]);
            corr[j] = __expf(m_run[j] - mn);
            m_run[j] = mn;
            l_run[j] *= corr[j];
        }
        #pragma unroll
        for (int n = 0; n < 4; ++n)
            #pragma unroll
            for (int j = 0; j < 4; ++j) acco[n][j] *= corr[j];
        #pragma unroll
        for (int n = 0; n < 4; ++n) {
            #pragma unroll
            for (int j = 0; j < 4; ++j) {
                float p = __expf(s[n][j] - m_run[j]);
                l_run[j] += p;
                Ps[wq * 16 + rg * 4 + j][n * 16 + c] = f2bf(p);
            }
        }
        #pragma unroll
        for (int kh = 0; kh < 2; ++kh) {
            bf16x8_t pa = *(const bf16x8_t*)&Ps[wq * 16 + fr][kh * 32 + fko];
            #pragma unroll
            for (int n = 0; n < 4; ++n) {
                bf16x8_t vb = *(const bf16x8_t*)&Vt[n * 16 + fr][kh * 32 + fko];
                acco[n] = __builtin_amdgcn_mfma_f32_16x16x32_bf16(pa, vb, acco[n], 0, 0, 0);
            }
        }
        __syncthreads();
    }
    #pragma unroll
    for (int j = 0; j < 4; ++j) {
        l_run[j] += __shfl_xor(l_run[j], 1);
        l_run[j] += __shfl_xor(l_run[j], 2);
        l_run[j] += __shfl_xor(l_run[j], 4);
        l_run[j] += __shfl_xor(l_run[j], 8);
    }
    #pragma unroll
    for (int n = 0; n < 4; ++n) {
        #pragma unroll
        for (int j = 0; j < 4; ++j) {
            float o = acco[n][j] / l_run[j];
            ao[(size_t)rowt[j] * D_DIM + h * HD_DIM + n * 16 + c] = o;
        }
    }
}

// ------------- SwiGLU elementwise ------------------------------------------
__global__ void silumul_kernel(const float* __restrict__ g1,
    const float* __restrict__ g3, float* __restrict__ out, int n)
{
    int i = blockIdx.x * blockDim.x + threadIdx.x;
    if (i < n) {
        float a = g1[i];
        out[i] = a / (1.f + __expf(-a)) * g3[i];
    }
}

extern "C" void kernel_launch(void* const* d_in, const int* in_sizes, int n_in,
                              void* d_out, int out_size, void* d_ws, size_t ws_size,
                              hipStream_t stream) {
    const float* x         = (const float*)d_in[0];
    const float* norm1_w   = (const float*)d_in[1];
    const float* norm2_w   = (const float*)d_in[2];
    const float* w_qkv     = (const float*)d_in[3];
    const float* q_norm_w  = (const float*)d_in[4];
    const float* k_norm_w  = (const float*)d_in[5];
    const float* gamma_w1  = (const float*)d_in[6];
    const float* gamma_w2  = (const float*)d_in[7];
    const float* m_persist = (const float*)d_in[8];
    const float* mem_gate  = (const float*)d_in[9];
    const float* w_o       = (const float*)d_in[10];
    const float* ffn_w1    = (const float*)d_in[11];
    const float* ffn_w3    = (const float*)d_in[12];
    const float* ffn_w2    = (const float*)d_in[13];
    float* out = (float*)d_out;
    char* ws = (char*)d_ws;

    const size_t MB = 1024 * 1024;
    float* h_buf  = (float*)(ws);            // [0,  8MB): h, later h2
    float* qkv    = (float*)(ws + 8  * MB);  // [8, 32MB): qkv; later ao; later G1
    float* qh     = (float*)(ws + 32 * MB);  // [32,40MB): q (H,S,HD)
    float* kh     = (float*)(ws + 40 * MB);  // [40,48MB): k (H,S,HD)
    float* vh     = (float*)(ws + 48 * MB);  // [48,56MB): v (H,S,HD)
    float* gammab = (float*)(ws + 56 * MB);  // 8KB gamma per token
    float* ao = qkv;
    float* G1 = qkv;
    float* G3 = qh;

    hipLaunchKernelGGL(rmsnorm_kernel, dim3(S_LEN), dim3(256), 0, stream, x, norm1_w, h_buf);
    hipLaunchKernelGGL(gemm_bf16_kernel, dim3(3 * D_DIM / GBN, S_LEN / GBM), dim3(256), 0, stream,
                       h_buf, w_qkv, (const float*)nullptr, qkv, S_LEN, 3 * D_DIM, D_DIM);
    hipLaunchKernelGGL(split_rope_kernel, dim3(S_LEN, H_NUM), dim3(64), 0, stream,
                       qkv, q_norm_w, k_norm_w, qh, kh, vh);
    hipLaunchKernelGGL(gamma_kernel, dim3(S_LEN), dim3(64), 0, stream,
                       h_buf, gamma_w1, gamma_w2, gammab);
    hipLaunchKernelGGL(omega_mfma_kernel, dim3(S_LEN / QBLK, H_NUM), dim3(256), 0, stream,
                       qh, kh, gammab, m_persist, mem_gate);
    hipLaunchKernelGGL(attn_mfma_kernel, dim3(S_LEN / QBLK, H_NUM), dim3(256), 0, stream,
                       qh, kh, vh, ao);
    hipLaunchKernelGGL(gemm_bf16_kernel, dim3(D_DIM / GBN, S_LEN / GBM), dim3(256), 0, stream,
                       ao, w_o, x, out, S_LEN, D_DIM, D_DIM);
    hipLaunchKernelGGL(rmsnorm_kernel, dim3(S_LEN), dim3(256), 0, stream, out, norm2_w, h_buf);
    int ffn_bx = (FFN_H + GBN - 1) / GBN;
    hipLaunchKernelGGL(gemm_bf16_kernel, dim3(ffn_bx, S_LEN / GBM), dim3(256), 0, stream,
                       h_buf, ffn_w1, (const float*)nullptr, G1, S_LEN, FFN_H, D_DIM);
    hipLaunchKernelGGL(gemm_bf16_kernel, dim3(ffn_bx, S_LEN / GBM), dim3(256), 0, stream,
                       h_buf, ffn_w3, (const float*)nullptr, G3, S_LEN, FFN_H, D_DIM);
    int nmid = S_LEN * FFN_H;
    hipLaunchKernelGGL(silumul_kernel, dim3((nmid + 255) / 256), dim3(256), 0, stream,
                       G1, G3, G1, nmid);
    hipLaunchKernelGGL(gemm_bf16_kernel, dim3(D_DIM / GBN, S_LEN / GBM), dim3(256), 0, stream,
                       G1, ffn_w2, out, out, S_LEN, D_DIM, FFN_H);
}

// Round 5
// 309.893 us; speedup vs baseline: 11.0940x; 2.7240x over previous
//
#include <hip/hip_runtime.h>
#include <hip/hip_bf16.h>

#define S_LEN 2048
#define D_DIM 1024
#define H_NUM 16
#define HD_DIM 64
#define GH_DIM 64
#define FFN_H 2730
#define FFNP  2816          // FFN_H padded to multiple of 128 (zero-filled)
#define CTX_W 512
#define L2LAM -0.00144341687f   // log2(0.999)

typedef unsigned short u16;
typedef __attribute__((ext_vector_type(8))) short bf16x8_t;
typedef __attribute__((ext_vector_type(4))) float f32x4_t;

__device__ inline float wave_sum(float v) {
    for (int off = 32; off; off >>= 1) v += __shfl_xor(v, off);
    return v;
}
__device__ inline u16 f2bf(float f) {
    unsigned int u = __float_as_uint(f);
    unsigned int r = u + 0x7FFFu + ((u >> 16) & 1u);
    return (u16)(r >> 16);
}
__device__ inline float bf2f(u16 u) {
    return __uint_as_float(((unsigned int)u) << 16);
}
__device__ inline void gload16(const void* g, void* l) {
    __builtin_amdgcn_global_load_lds(
        (const __attribute__((address_space(1))) void*)g,
        (__attribute__((address_space(3))) void*)l, 16, 0, 0);
}

// ---------------- RMSNorm (fp32 in -> bf16 out) -----------------------------
__global__ __launch_bounds__(256) void rmsnorm_bf_kernel(const float* __restrict__ in,
    const float* __restrict__ w, u16* __restrict__ out)
{
    int row = blockIdx.x;
    const float4* ir = reinterpret_cast<const float4*>(in + (size_t)row * D_DIM);
    float4 v = ir[threadIdx.x];
    float ss = v.x*v.x + v.y*v.y + v.z*v.z + v.w*v.w;
    ss = wave_sum(ss);
    __shared__ float wsum[4];
    if ((threadIdx.x & 63) == 0) wsum[threadIdx.x >> 6] = ss;
    __syncthreads();
    float tot = wsum[0] + wsum[1] + wsum[2] + wsum[3];
    float scale = rsqrtf(tot / (float)D_DIM + 1e-6f);
    const float4* wr = reinterpret_cast<const float4*>(w);
    float4 wv = wr[threadIdx.x];
    ushort4 o;
    o.x = f2bf(v.x * scale * wv.x); o.y = f2bf(v.y * scale * wv.y);
    o.z = f2bf(v.z * scale * wv.z); o.w = f2bf(v.w * scale * wv.w);
    *reinterpret_cast<ushort4*>(out + (size_t)row * D_DIM + threadIdx.x * 4) = o;
}

// ------------- transpose+convert: W[K][N] fp32 -> WT[N][Kp] bf16, 0-padded --
__global__ __launch_bounds__(256) void transpose_cvt_kernel(
    const float* __restrict__ src, u16* __restrict__ dst,
    int srcK, int srcN, int Kp, int rowOff)
{
    __shared__ float tile[32][33];
    int tx = threadIdx.x & 31, ty = threadIdx.x >> 5;
    int n0 = blockIdx.x * 32, k0 = blockIdx.y * 32;
    #pragma unroll
    for (int p = 0; p < 4; ++p) {
        int kk = ty + p * 8;
        int r = k0 + kk, c = n0 + tx;
        tile[kk][tx] = (r < srcK && c < srcN) ? src[(size_t)r * srcN + c] : 0.f;
    }
    __syncthreads();
    #pragma unroll
    for (int p = 0; p < 4; ++p) {
        int nn = ty + p * 8;
        dst[(size_t)(rowOff + n0 + nn) * Kp + k0 + tx] = f2bf(tile[tx][nn]);
    }
}

// ---------------- bf16 MFMA GEMM (all dims multiples of tile) ---------------
// A: M x K bf16 row-major.  B: N x K bf16 row-major (i.e. B^T of K x N).
// BN = 128 fixed, BK = 64 fixed, 256 threads = 4 waves (2x2).
template<int BM, bool OUT_BF, bool HAS_RES>
__global__ __launch_bounds__(256) void gemm_bb_kernel(
    const u16* __restrict__ A, const u16* __restrict__ B,
    const float* __restrict__ res, float* __restrict__ Cf, u16* __restrict__ Cb,
    int M, int N, int K)
{
    constexpr int MREP = BM / 32;      // per-wave 16-row fragments
    constexpr int ACH  = BM / 32;      // A 1KB-chunks per wave per K-step
    __shared__ u16 As[BM * 64];
    __shared__ u16 Bs[128 * 64];
    int tid = threadIdx.x, lane = tid & 63, wid = tid >> 6;
    int wr = wid >> 1, wc = wid & 1;
    int row0 = blockIdx.y * BM, col0 = blockIdx.x * 128;
    int l8 = lane >> 3, l7 = lane & 7;
    f32x4_t acc[MREP][4];
    #pragma unroll
    for (int i = 0; i < MREP; ++i)
        #pragma unroll
        for (int j = 0; j < 4; ++j) acc[i][j] = (f32x4_t)0.f;

    int fr = lane & 15, fo = (lane >> 4) * 8;
    for (int k0 = 0; k0 < K; k0 += 64) {
        #pragma unroll
        for (int i = 0; i < ACH; ++i) {
            int ch = wid * ACH + i;
            const u16* ga = A + (size_t)(row0 + ch * 8 + l8) * K + k0 + l7 * 8;
            gload16(ga, &As[ch * 512]);
        }
        #pragma unroll
        for (int i = 0; i < 4; ++i) {
            int ch = wid * 4 + i;
            const u16* gb = B + (size_t)(col0 + ch * 8 + l8) * K + k0 + l7 * 8;
            gload16(gb, &Bs[ch * 512]);
        }
        __syncthreads();
        #pragma unroll
        for (int khf = 0; khf < 2; ++khf) {
            bf16x8_t bfrag[4];
            #pragma unroll
            for (int ni = 0; ni < 4; ++ni)
                bfrag[ni] = *(const bf16x8_t*)&Bs[(wc * 64 + ni * 16 + fr) * 64 + khf * 32 + fo];
            #pragma unroll
            for (int mi = 0; mi < MREP; ++mi) {
                bf16x8_t af = *(const bf16x8_t*)&As[(wr * (BM / 2) + mi * 16 + fr) * 64 + khf * 32 + fo];
                #pragma unroll
                for (int ni = 0; ni < 4; ++ni)
                    acc[mi][ni] = __builtin_amdgcn_mfma_f32_16x16x32_bf16(
                        af, bfrag[ni], acc[mi][ni], 0, 0, 0);
            }
        }
        __syncthreads();
    }
    int dr = (lane >> 4) * 4, dc = lane & 15;
    #pragma unroll
    for (int mi = 0; mi < MREP; ++mi) {
        int gr = row0 + wr * (BM / 2) + mi * 16 + dr;
        #pragma unroll
        for (int ni = 0; ni < 4; ++ni) {
            int gc = col0 + wc * 64 + ni * 16 + dc;
            #pragma unroll
            for (int j = 0; j < 4; ++j) {
                size_t off = (size_t)(gr + j) * N + gc;
                if (OUT_BF) {
                    Cb[off] = f2bf(acc[mi][ni][j]);
                } else {
                    float v = acc[mi][ni][j];
                    if (HAS_RES) v += res[off];
                    Cf[off] = v;
                }
            }
        }
    }
}

// ------------- split qkv(bf16) + qk rmsnorm + RoPE --------------------------
// qh fp32 (H,S,HD);  kh,vh bf16 (H,S,HD)
__global__ __launch_bounds__(64) void split_rope_kernel(
    const u16* __restrict__ qkv, const float* __restrict__ qw,
    const float* __restrict__ kw, float* __restrict__ qhp,
    u16* __restrict__ khp, u16* __restrict__ vhp)
{
    int s = blockIdx.x, h = blockIdx.y, d = threadIdx.x;
    size_t base = (size_t)s * (3 * D_DIM) + h * HD_DIM + d;
    float qv = bf2f(qkv[base]);
    float kv = bf2f(qkv[base + D_DIM]);
    u16  vv = qkv[base + 2 * D_DIM];
    float sq = wave_sum(qv * qv);
    float qn = qv * rsqrtf(sq / (float)HD_DIM + 1e-6f) * qw[d];
    float sk = wave_sum(kv * kv);
    float kn = kv * rsqrtf(sk / (float)HD_DIM + 1e-6f) * kw[d];
    int j = d & 31;
    float inv = expf(-(float)j * (9.2103403719761836f / 32.0f));
    float ang = (float)s * inv;
    float cs = cosf(ang), sn = sinf(ang);
    float qp = __shfl_xor(qn, 32);
    float kp = __shfl_xor(kn, 32);
    float sgn = (d < 32) ? -1.f : 1.f;
    float qo = qn * cs + sgn * qp * sn;
    float ko = kn * cs + sgn * kp * sn;
    size_t ob = ((size_t)h * S_LEN + s) * HD_DIM + d;
    qhp[ob] = qo; khp[ob] = f2bf(ko); vhp[ob] = vv;
}

// ------------- gamma gate (bf16 h) ------------------------------------------
__global__ __launch_bounds__(64) void gamma_kernel(const u16* __restrict__ h,
    const float* __restrict__ w1, const float* __restrict__ w2,
    float* __restrict__ gamma)
{
    __shared__ float hl[D_DIM];
    int s = blockIdx.x, j = threadIdx.x;
    for (int k = j; k < D_DIM; k += 64) hl[k] = bf2f(h[(size_t)s * D_DIM + k]);
    __syncthreads();
    float acc = 0.f;
    for (int k = 0; k < D_DIM; ++k) acc += hl[k] * w1[k * GH_DIM + j];
    float z = acc / (1.f + __expf(-acc));
    float y = z * w2[j];
    float tot = wave_sum(y);
    if (j == 0) gamma[s] = 1.f / (1.f + __expf(-tot));
}

// ============ MFMA omega-rule: in-place q update (q fp32, K bf16) ===========
#define QBLK 64
#define KBLK 64
#define ALDK 72

__global__ __launch_bounds__(256) void omega_mfma_kernel(
    float* __restrict__ qhp, const u16* __restrict__ khp,
    const float* __restrict__ gammab, const float* __restrict__ mp,
    const float* __restrict__ mg)
{
    __shared__ u16 Ks[KBLK][ALDK];
    __shared__ u16 Kt[HD_DIM][ALDK];
    __shared__ u16 Ps[QBLK][ALDK];
    int tid = threadIdx.x, lane = tid & 63, wq = tid >> 6;
    int h = blockIdx.y;
    int qt = (h & 8) ? ((int)gridDim.x - 1 - blockIdx.x) : blockIdx.x;
    int q0 = qt * QBLK;
    int fr = lane & 15, fko = (lane >> 4) * 8;
    int c = lane & 15, rg = lane >> 4;
    int rowt[4];
    float rowf[4];
    #pragma unroll
    for (int j = 0; j < 4; ++j) {
        rowt[j] = q0 + wq * 16 + rg * 4 + j;
        rowf[j] = exp2f((float)(wq * 16 + rg * 4 + j) * L2LAM);
    }
    bf16x8_t qf[2];
    {
        const float* qrow = qhp + ((size_t)h * S_LEN + q0 + wq * 16 + fr) * HD_DIM;
        #pragma unroll
        for (int kh2 = 0; kh2 < 2; ++kh2) {
            float4 a = *(const float4*)(qrow + kh2 * 32 + fko);
            float4 b = *(const float4*)(qrow + kh2 * 32 + fko + 4);
            bf16x8_t f;
            f[0]=f2bf(a.x); f[1]=f2bf(a.y); f[2]=f2bf(a.z); f[3]=f2bf(a.w);
            f[4]=f2bf(b.x); f[5]=f2bf(b.y); f[6]=f2bf(b.z); f[7]=f2bf(b.w);
            qf[kh2] = f;
        }
    }
    f32x4_t accc[4];
    #pragma unroll
    for (int n = 0; n < 4; ++n) accc[n] = (f32x4_t)0.f;
    float wsum[4] = {0.f, 0.f, 0.f, 0.f};
    int kt0 = 0;
    if (q0 - (CTX_W - 1) > 0) kt0 = (q0 - (CTX_W - 1)) / KBLK;
    int si = tid >> 2, sdb = (tid & 3) * 16;
    for (int kt = kt0; kt <= qt; ++kt) {
        int k0 = kt * KBLK;
        {
            union { u16 u[16]; bf16x8_t v[2]; } kq;
            const u16* kr = khp + ((size_t)h * S_LEN + k0 + si) * HD_DIM + sdb;
            kq.v[0] = *(const bf16x8_t*)kr;
            kq.v[1] = *(const bf16x8_t*)(kr + 8);
            *(bf16x8_t*)&Ks[si][sdb]     = kq.v[0];
            *(bf16x8_t*)&Ks[si][sdb + 8] = kq.v[1];
            #pragma unroll
            for (int e = 0; e < 16; ++e) Kt[sdb + e][si] = kq.u[e];
        }
        __syncthreads();
        f32x4_t s[4];
        #pragma unroll
        for (int n = 0; n < 4; ++n) s[n] = (f32x4_t)0.f;
        #pragma unroll
        for (int kh2 = 0; kh2 < 2; ++kh2) {
            #pragma unroll
            for (int n = 0; n < 4; ++n) {
                bf16x8_t kb = *(const bf16x8_t*)&Ks[n * 16 + fr][kh2 * 32 + fko];
                s[n] = __builtin_amdgcn_mfma_f32_16x16x32_bf16(qf[kh2], kb, s[n], 0, 0, 0);
            }
        }
        #pragma unroll
        for (int n = 0; n < 4; ++n) {
            int icol = k0 + n * 16 + c;
            float colf = exp2f((float)(q0 - icol) * L2LAM) * gammab[icol];
            #pragma unroll
            for (int j = 0; j < 4; ++j) {
                int delta = rowt[j] - icol;
                float w = (delta >= 0 && delta < CTX_W) ? rowf[j] * colf : 0.f;
                wsum[j] += w;
                Ps[wq * 16 + rg * 4 + j][n * 16 + c] = f2bf(w * s[n][j]);
            }
        }
        #pragma unroll
        for (int kh2 = 0; kh2 < 2; ++kh2) {
            bf16x8_t pa = *(const bf16x8_t*)&Ps[wq * 16 + fr][kh2 * 32 + fko];
            #pragma unroll
            for (int n = 0; n < 4; ++n) {
                bf16x8_t kb = *(const bf16x8_t*)&Kt[n * 16 + fr][kh2 * 32 + fko];
                accc[n] = __builtin_amdgcn_mfma_f32_16x16x32_bf16(pa, kb, accc[n], 0, 0, 0);
            }
        }
        __syncthreads();
    }
    f32x4_t pacc[4];
    #pragma unroll
    for (int n = 0; n < 4; ++n) pacc[n] = (f32x4_t)0.f;
    const float* mph = mp + (size_t)h * HD_DIM * HD_DIM;
    #pragma unroll
    for (int kh2 = 0; kh2 < 2; ++kh2) {
        #pragma unroll
        for (int n = 0; n < 4; ++n) {
            const float* br = mph + (size_t)(n * 16 + fr) * HD_DIM + kh2 * 32 + fko;
            float4 a = *(const float4*)br;
            float4 b = *(const float4*)(br + 4);
            bf16x8_t f;
            f[0]=f2bf(a.x); f[1]=f2bf(a.y); f[2]=f2bf(a.z); f[3]=f2bf(a.w);
            f[4]=f2bf(b.x); f[5]=f2bf(b.y); f[6]=f2bf(b.z); f[7]=f2bf(b.w);
            pacc[n] = __builtin_amdgcn_mfma_f32_16x16x32_bf16(qf[kh2], f, pacc[n], 0, 0, 0);
        }
    }
    #pragma unroll
    for (int j = 0; j < 4; ++j) {
        wsum[j] += __shfl_xor(wsum[j], 1);
        wsum[j] += __shfl_xor(wsum[j], 2);
        wsum[j] += __shfl_xor(wsum[j], 4);
        wsum[j] += __shfl_xor(wsum[j], 8);
    }
    float gate = 1.f / (1.f + __expf(-mg[0]));
    float keep = 1.f - gate;
    #pragma unroll
    for (int n = 0; n < 4; ++n) {
        #pragma unroll
        for (int j = 0; j < 4; ++j) {
            size_t off = ((size_t)h * S_LEN + rowt[j]) * HD_DIM + n * 16 + c;
            float qold = qhp[off];
            qhp[off] = keep * qold +
                       gate * (pacc[n][j] + accc[n][j]) / (1.f + wsum[j]);
        }
    }
}

// ============ MFMA flash attention (q fp32, K/V bf16, ao bf16) ==============
__global__ __launch_bounds__(256) void attn_mfma_kernel(
    const float* __restrict__ qhp, const u16* __restrict__ khp,
    const u16* __restrict__ vhp, u16* __restrict__ ao)
{
    __shared__ u16 Ks[KBLK][ALDK];
    __shared__ u16 Vt[HD_DIM][ALDK];
    __shared__ u16 Ps[QBLK][ALDK];
    int tid = threadIdx.x, lane = tid & 63, wq = tid >> 6;
    int h = blockIdx.y;
    int qt = (h & 8) ? ((int)gridDim.x - 1 - blockIdx.x) : blockIdx.x;
    int q0 = qt * QBLK;
    int fr = lane & 15, fko = (lane >> 4) * 8;
    int c = lane & 15, rg = lane >> 4;
    int rowt[4];
    #pragma unroll
    for (int j = 0; j < 4; ++j) rowt[j] = q0 + wq * 16 + rg * 4 + j;
    bf16x8_t qf[2];
    {
        const float* qrow = qhp + ((size_t)h * S_LEN + q0 + wq * 16 + fr) * HD_DIM;
        #pragma unroll
        for (int kh2 = 0; kh2 < 2; ++kh2) {
            float4 a = *(const float4*)(qrow + kh2 * 32 + fko);
            float4 b = *(const float4*)(qrow + kh2 * 32 + fko + 4);
            bf16x8_t f;
            f[0]=f2bf(a.x); f[1]=f2bf(a.y); f[2]=f2bf(a.z); f[3]=f2bf(a.w);
            f[4]=f2bf(b.x); f[5]=f2bf(b.y); f[6]=f2bf(b.z); f[7]=f2bf(b.w);
            qf[kh2] = f;
        }
    }
    f32x4_t acco[4];
    #pragma unroll
    for (int n = 0; n < 4; ++n) acco[n] = (f32x4_t)0.f;
    float m_run[4] = {-1e30f, -1e30f, -1e30f, -1e30f};
    float l_run[4] = {0.f, 0.f, 0.f, 0.f};
    int si = tid >> 2, sdb = (tid & 3) * 16;
    for (int kt = 0; kt <= qt; ++kt) {
        int k0 = kt * KBLK;
        {
            union { u16 u[16]; bf16x8_t v[2]; } kq, vq;
            const u16* kr = khp + ((size_t)h * S_LEN + k0 + si) * HD_DIM + sdb;
            const u16* vr = vhp + ((size_t)h * S_LEN + k0 + si) * HD_DIM + sdb;
            kq.v[0] = *(const bf16x8_t*)kr;
            kq.v[1] = *(const bf16x8_t*)(kr + 8);
            vq.v[0] = *(const bf16x8_t*)vr;
            vq.v[1] = *(const bf16x8_t*)(vr + 8);
            *(bf16x8_t*)&Ks[si][sdb]     = kq.v[0];
            *(bf16x8_t*)&Ks[si][sdb + 8] = kq.v[1];
            #pragma unroll
            for (int e = 0; e < 16; ++e) Vt[sdb + e][si] = vq.u[e];
        }
        __syncthreads();
        f32x4_t s[4];
        #pragma unroll
        for (int n = 0; n < 4; ++n) s[n] = (f32x4_t)0.f;
        #pragma unroll
        for (int kh2 = 0; kh2 < 2; ++kh2) {
            #pragma unroll
            for (int n = 0; n < 4; ++n) {
                bf16x8_t kb = *(const bf16x8_t*)&Ks[n * 16 + fr][kh2 * 32 + fko];
                s[n] = __builtin_amdgcn_mfma_f32_16x16x32_bf16(qf[kh2], kb, s[n], 0, 0, 0);
            }
        }
        float tmax[4] = {-1e30f, -1e30f, -1e30f, -1e30f};
        #pragma unroll
        for (int n = 0; n < 4; ++n) {
            int icol = k0 + n * 16 + c;
            #pragma unroll
            for (int j = 0; j < 4; ++j) {
                float v = s[n][j] * 0.125f;
                if (icol > rowt[j]) v = -1e30f;
                s[n][j] = v;
                tmax[j] = fmaxf(tmax[j], v);
            }
        }
        #pragma unroll
        for (int j = 0; j < 4; ++j) {
            tmax[j] = fmaxf(tmax[j], __shfl_xor(tmax[j], 1));
            tmax[j] = fmaxf(tmax[j], __shfl_xor(tmax[j], 2));
            tmax[j] = fmaxf(tmax[j], __shfl_xor(tmax[j], 4));
            tmax[j] = fmaxf(tmax[j], __shfl_xor(tmax[j], 8));
        }
        float corr[4];
        #pragma unroll
        for (int j = 0; j < 4; ++j) {
            float mn = fmaxf(m_run[j], tmax[j]);
            corr[j] = __expf(m_run[j] - mn);
            m_run[j] = mn;
            l_run[j] *= corr[j];
        }
        #pragma unroll
        for (int n = 0; n < 4; ++n)
            #pragma unroll
            for (int j = 0; j < 4; ++j) acco[n][j] *= corr[j];
        #pragma unroll
        for (int n = 0; n < 4; ++n) {
            #pragma unroll
            for (int j = 0; j < 4; ++j) {
                float p = __expf(s[n][j] - m_run[j]);
                l_run[j] += p;
                Ps[wq * 16 + rg * 4 + j][n * 16 + c] = f2bf(p);
            }
        }
        #pragma unroll
        for (int kh2 = 0; kh2 < 2; ++kh2) {
            bf16x8_t pa = *(const bf16x8_t*)&Ps[wq * 16 + fr][kh2 * 32 + fko];
            #pragma unroll
            for (int n = 0; n < 4; ++n) {
                bf16x8_t vb = *(const bf16x8_t*)&Vt[n * 16 + fr][kh2 * 32 + fko];
                acco[n] = __builtin_amdgcn_mfma_f32_16x16x32_bf16(pa, vb, acco[n], 0, 0, 0);
            }
        }
        __syncthreads();
    }
    #pragma unroll
    for (int j = 0; j < 4; ++j) {
        l_run[j] += __shfl_xor(l_run[j], 1);
        l_run[j] += __shfl_xor(l_run[j], 2);
        l_run[j] += __shfl_xor(l_run[j], 4);
        l_run[j] += __shfl_xor(l_run[j], 8);
    }
    #pragma unroll
    for (int n = 0; n < 4; ++n) {
        #pragma unroll
        for (int j = 0; j < 4; ++j) {
            float o = acco[n][j] / l_run[j];
            ao[(size_t)rowt[j] * D_DIM + h * HD_DIM + n * 16 + c] = f2bf(o);
        }
    }
}

// ------------- fused SwiGLU: mid = silu(G1)*G3 (bf16 in/out, padded) --------
__global__ __launch_bounds__(256) void silumul_bf_kernel(const u16* __restrict__ G,
    u16* __restrict__ mid)
{
    int m = blockIdx.x;
    const u16* g1 = G + (size_t)m * (2 * FFNP);
    const u16* g3 = g1 + FFNP;
    u16* mo = mid + (size_t)m * FFNP;
    for (int ci = threadIdx.x; ci < FFNP / 8; ci += 256) {
        bf16x8_t a = *(const bf16x8_t*)(g1 + ci * 8);
        bf16x8_t b = *(const bf16x8_t*)(g3 + ci * 8);
        bf16x8_t o;
        #pragma unroll
        for (int e = 0; e < 8; ++e) {
            float fa = bf2f((u16)a[e]);
            float fb = bf2f((u16)b[e]);
            o[e] = (short)f2bf(fa / (1.f + __expf(-fa)) * fb);
        }
        *(bf16x8_t*)(mo + ci * 8) = o;
    }
}

extern "C" void kernel_launch(void* const* d_in, const int* in_sizes, int n_in,
                              void* d_out, int out_size, void* d_ws, size_t ws_size,
                              hipStream_t stream) {
    const float* x         = (const float*)d_in[0];
    const float* norm1_w   = (const float*)d_in[1];
    const float* norm2_w   = (const float*)d_in[2];
    const float* w_qkv     = (const float*)d_in[3];
    const float* q_norm_w  = (const float*)d_in[4];
    const float* k_norm_w  = (const float*)d_in[5];
    const float* gamma_w1  = (const float*)d_in[6];
    const float* gamma_w2  = (const float*)d_in[7];
    const float* m_persist = (const float*)d_in[8];
    const float* mem_gate  = (const float*)d_in[9];
    const float* w_o       = (const float*)d_in[10];
    const float* ffn_w1    = (const float*)d_in[11];
    const float* ffn_w3    = (const float*)d_in[12];
    const float* ffn_w2    = (const float*)d_in[13];
    float* out = (float*)d_out;
    char* ws = (char*)d_ws;

    const size_t MB = 1024 * 1024;
    u16*   h_bf   = (u16*)(ws);                       // [0,4MB) h / h2
    u16*   wqT    = (u16*)(ws + 4 * MB);              // [4,10) wqT; dead after qkv gemm
    u16*   woT    = (u16*)(ws + 10 * MB);             // [10,12) dead after wo gemm
    u16*   w13T   = (u16*)(ws + 12 * MB);             // [12,23) dead after ffn13 gemm
    u16*   w2T    = (u16*)(ws + 23 * MB);             // [23,28.5)
    u16*   qkv_bf = (u16*)(ws + 29884416);            // [28.5,40.5) dead after split
    float* qh     = (float*)(ws + 42467328);          // [40.5,48.5) dead after attn
    u16*   kh     = (u16*)(ws + 50855936);            // [48.5,52.5) dead after attn
    u16*   vh     = (u16*)(ws + 55050240);            // [52.5,56.5) dead after attn
    float* gammab = (float*)(ws + 59244544);          // [56.5,+8KB)
    u16*   ao_bf  = (u16*)(ws + 29884416);            // reuse qkv region [28.5,32.5)
    u16*   G_bf   = (u16*)(ws + 34078720);            // [32.5,54.5) (qh/kh/vh dead)
    u16*   mid_bf = (u16*)(ws + 4 * MB);              // [4,15) (wqT/woT/w13T-head dead)

    // --- weight transposes/conversions (independent of activations) ---------
    hipLaunchKernelGGL(transpose_cvt_kernel, dim3(96, 32), dim3(256), 0, stream,
                       w_qkv, wqT, D_DIM, 3 * D_DIM, D_DIM, 0);
    hipLaunchKernelGGL(transpose_cvt_kernel, dim3(32, 32), dim3(256), 0, stream,
                       w_o, woT, D_DIM, D_DIM, D_DIM, 0);
    hipLaunchKernelGGL(transpose_cvt_kernel, dim3(88, 32), dim3(256), 0, stream,
                       ffn_w1, w13T, D_DIM, FFN_H, D_DIM, 0);
    hipLaunchKernelGGL(transpose_cvt_kernel, dim3(88, 32), dim3(256), 0, stream,
                       ffn_w3, w13T, D_DIM, FFN_H, D_DIM, FFNP);
    hipLaunchKernelGGL(transpose_cvt_kernel, dim3(32, 88), dim3(256), 0, stream,
                       ffn_w2, w2T, FFN_H, D_DIM, FFNP, 0);

    // --- forward pass --------------------------------------------------------
    hipLaunchKernelGGL(rmsnorm_bf_kernel, dim3(S_LEN), dim3(256), 0, stream,
                       x, norm1_w, h_bf);
    hipLaunchKernelGGL((gemm_bb_kernel<128, true, false>), dim3(24, 16), dim3(256), 0, stream,
                       h_bf, wqT, (const float*)nullptr, (float*)nullptr, qkv_bf,
                       S_LEN, 3 * D_DIM, D_DIM);
    hipLaunchKernelGGL(split_rope_kernel, dim3(S_LEN, H_NUM), dim3(64), 0, stream,
                       qkv_bf, q_norm_w, k_norm_w, qh, kh, vh);
    hipLaunchKernelGGL(gamma_kernel, dim3(S_LEN), dim3(64), 0, stream,
                       h_bf, gamma_w1, gamma_w2, gammab);
    hipLaunchKernelGGL(omega_mfma_kernel, dim3(S_LEN / QBLK, H_NUM), dim3(256), 0, stream,
                       qh, kh, gammab, m_persist, mem_gate);
    hipLaunchKernelGGL(attn_mfma_kernel, dim3(S_LEN / QBLK, H_NUM), dim3(256), 0, stream,
                       qh, kh, vh, ao_bf);
    hipLaunchKernelGGL((gemm_bb_kernel<64, false, true>), dim3(8, 32), dim3(256), 0, stream,
                       ao_bf, woT, x, out, (u16*)nullptr, S_LEN, D_DIM, D_DIM);
    hipLaunchKernelGGL(rmsnorm_bf_kernel, dim3(S_LEN), dim3(256), 0, stream,
                       out, norm2_w, h_bf);
    hipLaunchKernelGGL((gemm_bb_kernel<128, true, false>), dim3(44, 16), dim3(256), 0, stream,
                       h_bf, w13T, (const float*)nullptr, (float*)nullptr, G_bf,
                       S_LEN, 2 * FFNP, D_DIM);
    hipLaunchKernelGGL(silumul_bf_kernel, dim3(S_LEN), dim3(256), 0, stream,
                       G_bf, mid_bf);
    hipLaunchKernelGGL((gemm_bb_kernel<64, false, true>), dim3(8, 32), dim3(256), 0, stream,
                       mid_bf, w2T, out, out, (u16*)nullptr, S_LEN, D_DIM, FFNP);
}

// Round 6
// 293.676 us; speedup vs baseline: 11.7066x; 1.0552x over previous
//
#include <hip/hip_runtime.h>
#include <hip/hip_bf16.h>

#define S_LEN 2048
#define D_DIM 1024
#define H_NUM 16
#define HD_DIM 64
#define GH_DIM 64
#define FFN_H 2730
#define FFNP  2816          // FFN_H padded to multiple of 128 (zero-filled)
#define CTX_W 512
#define L2LAM -0.00144341687f   // log2(0.999)
#define QBLK 64
#define KBLK 64
#define ALDK 72             // padded LDS row stride (144B) -> conflict-free b128 reads

typedef unsigned short u16;
typedef __attribute__((ext_vector_type(8))) short bf16x8_t;
typedef __attribute__((ext_vector_type(4))) float f32x4_t;

__device__ inline float wave_sum(float v) {
    for (int off = 32; off; off >>= 1) v += __shfl_xor(v, off);
    return v;
}
__device__ inline u16 f2bf(float f) {
    unsigned int u = __float_as_uint(f);
    unsigned int r = u + 0x7FFFu + ((u >> 16) & 1u);
    return (u16)(r >> 16);
}
__device__ inline float bf2f(u16 u) {
    return __uint_as_float(((unsigned int)u) << 16);
}
__device__ inline void gload16(const void* g, void* l) {
    __builtin_amdgcn_global_load_lds(
        (const __attribute__((address_space(1))) void*)g,
        (__attribute__((address_space(3))) void*)l, 16, 0, 0);
}

// ---------------- RMSNorm (fp32 in -> bf16 out) -----------------------------
__global__ __launch_bounds__(256) void rmsnorm_bf_kernel(const float* __restrict__ in,
    const float* __restrict__ w, u16* __restrict__ out)
{
    int row = blockIdx.x;
    const float4* ir = reinterpret_cast<const float4*>(in + (size_t)row * D_DIM);
    float4 v = ir[threadIdx.x];
    float ss = v.x*v.x + v.y*v.y + v.z*v.z + v.w*v.w;
    ss = wave_sum(ss);
    __shared__ float wsum[4];
    if ((threadIdx.x & 63) == 0) wsum[threadIdx.x >> 6] = ss;
    __syncthreads();
    float tot = wsum[0] + wsum[1] + wsum[2] + wsum[3];
    float scale = rsqrtf(tot / (float)D_DIM + 1e-6f);
    const float4* wr = reinterpret_cast<const float4*>(w);
    float4 wv = wr[threadIdx.x];
    ushort4 o;
    o.x = f2bf(v.x * scale * wv.x); o.y = f2bf(v.y * scale * wv.y);
    o.z = f2bf(v.z * scale * wv.z); o.w = f2bf(v.w * scale * wv.w);
    *reinterpret_cast<ushort4*>(out + (size_t)row * D_DIM + threadIdx.x * 4) = o;
}

// ------------- transpose+convert: W[K][N] fp32 -> WT[N][Kp] bf16, 0-padded --
__global__ __launch_bounds__(256) void transpose_cvt_kernel(
    const float* __restrict__ src, u16* __restrict__ dst,
    int srcK, int srcN, int Kp, int rowOff)
{
    __shared__ float tile[32][33];
    int tx = threadIdx.x & 31, ty = threadIdx.x >> 5;
    int n0 = blockIdx.x * 32, k0 = blockIdx.y * 32;
    #pragma unroll
    for (int p = 0; p < 4; ++p) {
        int kk = ty + p * 8;
        int r = k0 + kk, c = n0 + tx;
        tile[kk][tx] = (r < srcK && c < srcN) ? src[(size_t)r * srcN + c] : 0.f;
    }
    __syncthreads();
    #pragma unroll
    for (int p = 0; p < 4; ++p) {
        int nn = ty + p * 8;
        dst[(size_t)(rowOff + n0 + nn) * Kp + k0 + tx] = f2bf(tile[tx][nn]);
    }
}

// ------------- transpose bf16 K,V: (H,S,64) -> (H,64,S) ---------------------
__global__ __launch_bounds__(256) void transpose_kv_kernel(
    const u16* __restrict__ kh, const u16* __restrict__ vh,
    u16* __restrict__ khT, u16* __restrict__ vhT)
{
    __shared__ u16 tk[64][ALDK];
    __shared__ u16 tv[64][ALDK];
    int h = blockIdx.y;
    int s0 = blockIdx.x * 64;
    int tid = threadIdx.x;
    int r = tid >> 2, cc = (tid & 3) * 16;
    const u16* kp = kh + ((size_t)h * S_LEN + s0 + r) * HD_DIM + cc;
    const u16* vp = vh + ((size_t)h * S_LEN + s0 + r) * HD_DIM + cc;
    *(bf16x8_t*)&tk[r][cc]     = *(const bf16x8_t*)kp;
    *(bf16x8_t*)&tk[r][cc + 8] = *(const bf16x8_t*)(kp + 8);
    *(bf16x8_t*)&tv[r][cc]     = *(const bf16x8_t*)vp;
    *(bf16x8_t*)&tv[r][cc + 8] = *(const bf16x8_t*)(vp + 8);
    __syncthreads();
    union { u16 u[16]; bf16x8_t v[2]; } ok, ov;
    #pragma unroll
    for (int e = 0; e < 16; ++e) { ok.u[e] = tk[cc + e][r]; ov.u[e] = tv[cc + e][r]; }
    u16* kd = khT + ((size_t)h * HD_DIM + r) * S_LEN + s0 + cc;
    u16* vd = vhT + ((size_t)h * HD_DIM + r) * S_LEN + s0 + cc;
    *(bf16x8_t*)kd       = ok.v[0];
    *(bf16x8_t*)(kd + 8) = ok.v[1];
    *(bf16x8_t*)vd       = ov.v[0];
    *(bf16x8_t*)(vd + 8) = ov.v[1];
}

// ---------------- bf16 MFMA GEMM (all dims multiples of tile) ---------------
template<int BM, bool OUT_BF, bool HAS_RES>
__global__ __launch_bounds__(256) void gemm_bb_kernel(
    const u16* __restrict__ A, const u16* __restrict__ B,
    const float* __restrict__ res, float* __restrict__ Cf, u16* __restrict__ Cb,
    int M, int N, int K)
{
    constexpr int MREP = BM / 32;
    constexpr int ACH  = BM / 32;
    __shared__ u16 As[BM * 64];
    __shared__ u16 Bs[128 * 64];
    int tid = threadIdx.x, lane = tid & 63, wid = tid >> 6;
    int wr = wid >> 1, wc = wid & 1;
    int row0 = blockIdx.y * BM, col0 = blockIdx.x * 128;
    int l8 = lane >> 3, l7 = lane & 7;
    f32x4_t acc[MREP][4];
    #pragma unroll
    for (int i = 0; i < MREP; ++i)
        #pragma unroll
        for (int j = 0; j < 4; ++j) acc[i][j] = (f32x4_t)0.f;

    int fr = lane & 15, fo = (lane >> 4) * 8;
    for (int k0 = 0; k0 < K; k0 += 64) {
        #pragma unroll
        for (int i = 0; i < ACH; ++i) {
            int ch = wid * ACH + i;
            const u16* ga = A + (size_t)(row0 + ch * 8 + l8) * K + k0 + l7 * 8;
            gload16(ga, &As[ch * 512]);
        }
        #pragma unroll
        for (int i = 0; i < 4; ++i) {
            int ch = wid * 4 + i;
            const u16* gb = B + (size_t)(col0 + ch * 8 + l8) * K + k0 + l7 * 8;
            gload16(gb, &Bs[ch * 512]);
        }
        __syncthreads();
        #pragma unroll
        for (int khf = 0; khf < 2; ++khf) {
            bf16x8_t bfrag[4];
            #pragma unroll
            for (int ni = 0; ni < 4; ++ni)
                bfrag[ni] = *(const bf16x8_t*)&Bs[(wc * 64 + ni * 16 + fr) * 64 + khf * 32 + fo];
            #pragma unroll
            for (int mi = 0; mi < MREP; ++mi) {
                bf16x8_t af = *(const bf16x8_t*)&As[(wr * (BM / 2) + mi * 16 + fr) * 64 + khf * 32 + fo];
                #pragma unroll
                for (int ni = 0; ni < 4; ++ni)
                    acc[mi][ni] = __builtin_amdgcn_mfma_f32_16x16x32_bf16(
                        af, bfrag[ni], acc[mi][ni], 0, 0, 0);
            }
        }
        __syncthreads();
    }
    int dr = (lane >> 4) * 4, dc = lane & 15;
    #pragma unroll
    for (int mi = 0; mi < MREP; ++mi) {
        int gr = row0 + wr * (BM / 2) + mi * 16 + dr;
        #pragma unroll
        for (int ni = 0; ni < 4; ++ni) {
            int gc = col0 + wc * 64 + ni * 16 + dc;
            #pragma unroll
            for (int j = 0; j < 4; ++j) {
                size_t off = (size_t)(gr + j) * N + gc;
                if (OUT_BF) {
                    Cb[off] = f2bf(acc[mi][ni][j]);
                } else {
                    float v = acc[mi][ni][j];
                    if (HAS_RES) v += res[off];
                    Cf[off] = v;
                }
            }
        }
    }
}

// ------------- split qkv(bf16) + qk rmsnorm + RoPE (4 waves/block) ----------
__global__ __launch_bounds__(256) void split_rope_kernel(
    const u16* __restrict__ qkv, const float* __restrict__ qw,
    const float* __restrict__ kw, float* __restrict__ qhp,
    u16* __restrict__ khp, u16* __restrict__ vhp)
{
    int wq = threadIdx.x >> 6, d = threadIdx.x & 63;
    int s = blockIdx.x * 4 + wq, h = blockIdx.y;
    size_t base = (size_t)s * (3 * D_DIM) + h * HD_DIM + d;
    float qv = bf2f(qkv[base]);
    float kv = bf2f(qkv[base + D_DIM]);
    u16  vv = qkv[base + 2 * D_DIM];
    float sq = wave_sum(qv * qv);
    float qn = qv * rsqrtf(sq / (float)HD_DIM + 1e-6f) * qw[d];
    float sk = wave_sum(kv * kv);
    float kn = kv * rsqrtf(sk / (float)HD_DIM + 1e-6f) * kw[d];
    int j = d & 31;
    float inv = expf(-(float)j * (9.2103403719761836f / 32.0f));
    float ang = (float)s * inv;
    float cs = cosf(ang), sn = sinf(ang);
    float qp = __shfl_xor(qn, 32);
    float kp = __shfl_xor(kn, 32);
    float sgn = (d < 32) ? -1.f : 1.f;
    float qo = qn * cs + sgn * qp * sn;
    float ko = kn * cs + sgn * kp * sn;
    size_t ob = ((size_t)h * S_LEN + s) * HD_DIM + d;
    qhp[ob] = qo; khp[ob] = f2bf(ko); vhp[ob] = vv;
}

// ------------- gamma gate (4-wave parallel) ---------------------------------
__global__ __launch_bounds__(256) void gamma_kernel(const u16* __restrict__ h,
    const float* __restrict__ w1, const float* __restrict__ w2,
    float* __restrict__ gamma)
{
    __shared__ float hl[D_DIM];
    __shared__ float part[4][GH_DIM];
    int s = blockIdx.x, tid = threadIdx.x, lane = tid & 63, w = tid >> 6;
    {
        ushort4 v = *(const ushort4*)(h + (size_t)s * D_DIM + tid * 4);
        hl[tid*4+0] = bf2f(v.x); hl[tid*4+1] = bf2f(v.y);
        hl[tid*4+2] = bf2f(v.z); hl[tid*4+3] = bf2f(v.w);
    }
    __syncthreads();
    float acc = 0.f;
    #pragma unroll 8
    for (int k = w * 256; k < w * 256 + 256; ++k)
        acc += hl[k] * w1[k * GH_DIM + lane];
    part[w][lane] = acc;
    __syncthreads();
    if (w == 0) {
        float tot = part[0][lane] + part[1][lane] + part[2][lane] + part[3][lane];
        float z = tot / (1.f + __expf(-tot));
        float y = z * w2[lane];
        float t2 = wave_sum(y);
        if (lane == 0) gamma[s] = 1.f / (1.f + __expf(-t2));
    }
}

// ============ FUSED omega-rule + flash attention ============================
// One block per (q-tile, head). Omega consumes q_old (fp32), produces q_new in
// registers; attention consumes q_new directly. K/V^T staged vectorized; attn
// loop double-buffered with async load-early/write-late staging.
__global__ __launch_bounds__(256) void fused_omega_attn_kernel(
    const float* __restrict__ qhp, const u16* __restrict__ khp,
    const u16* __restrict__ khT, const u16* __restrict__ vhT,
    const float* __restrict__ gammab, const float* __restrict__ mp,
    const float* __restrict__ mg, u16* __restrict__ ao)
{
    __shared__ u16 Ks[2][KBLK][ALDK];
    __shared__ u16 Xt[2][KBLK][ALDK];
    __shared__ u16 Ps[QBLK][ALDK];
    const int tid = threadIdx.x, lane = tid & 63, wq = tid >> 6;
    const int h = blockIdx.y;
    const int qt = (h & 8) ? (S_LEN / QBLK - 1 - (int)blockIdx.x) : (int)blockIdx.x;
    const int q0 = qt * QBLK;
    const int fr = lane & 15, fko = (lane >> 4) * 8;
    const int c = lane & 15, rg = lane >> 4;
    const int si = tid >> 2, sdb = (tid & 3) * 16;
    const size_t hS = (size_t)h * S_LEN;
    const size_t hD = (size_t)h * HD_DIM;

    int rowt[4]; float rowf[4];
    #pragma unroll
    for (int j = 0; j < 4; ++j) {
        rowt[j] = q0 + wq * 16 + rg * 4 + j;
        rowf[j] = exp2f((float)(wq * 16 + rg * 4 + j) * L2LAM);
    }
    // q_old A-fragments
    bf16x8_t qf[2];
    {
        const float* qrow = qhp + (hS + q0 + wq * 16 + fr) * HD_DIM;
        #pragma unroll
        for (int u = 0; u < 2; ++u) {
            float4 a = *(const float4*)(qrow + u * 32 + fko);
            float4 b = *(const float4*)(qrow + u * 32 + fko + 4);
            bf16x8_t f;
            f[0]=f2bf(a.x); f[1]=f2bf(a.y); f[2]=f2bf(a.z); f[3]=f2bf(a.w);
            f[4]=f2bf(b.x); f[5]=f2bf(b.y); f[6]=f2bf(b.z); f[7]=f2bf(b.w);
            qf[u] = f;
        }
    }
    // ---------------- omega phase ----------------
    f32x4_t accc[4];
    #pragma unroll
    for (int n = 0; n < 4; ++n) accc[n] = (f32x4_t)0.f;
    float wsum[4] = {0.f, 0.f, 0.f, 0.f};
    int kt0 = (q0 > (CTX_W - 1)) ? (q0 - (CTX_W - 1)) / KBLK : 0;
    for (int kt = kt0; kt <= qt; ++kt) {
        const int k0 = kt * KBLK;
        {
            const u16* gk = khp + (hS + k0 + si) * HD_DIM + sdb;
            const u16* gx = khT + (hD + si) * S_LEN + k0 + sdb;
            bf16x8_t a0 = *(const bf16x8_t*)gk;
            bf16x8_t a1 = *(const bf16x8_t*)(gk + 8);
            bf16x8_t b0 = *(const bf16x8_t*)gx;
            bf16x8_t b1 = *(const bf16x8_t*)(gx + 8);
            *(bf16x8_t*)&Ks[0][si][sdb]     = a0;
            *(bf16x8_t*)&Ks[0][si][sdb + 8] = a1;
            *(bf16x8_t*)&Xt[0][si][sdb]     = b0;
            *(bf16x8_t*)&Xt[0][si][sdb + 8] = b1;
        }
        __syncthreads();
        f32x4_t s[4];
        #pragma unroll
        for (int n = 0; n < 4; ++n) s[n] = (f32x4_t)0.f;
        #pragma unroll
        for (int u = 0; u < 2; ++u)
            #pragma unroll
            for (int n = 0; n < 4; ++n) {
                bf16x8_t kb = *(const bf16x8_t*)&Ks[0][n * 16 + fr][u * 32 + fko];
                s[n] = __builtin_amdgcn_mfma_f32_16x16x32_bf16(qf[u], kb, s[n], 0, 0, 0);
            }
        #pragma unroll
        for (int n = 0; n < 4; ++n) {
            int icol = k0 + n * 16 + c;
            float colf = exp2f((float)(q0 - icol) * L2LAM) * gammab[icol];
            #pragma unroll
            for (int j = 0; j < 4; ++j) {
                int delta = rowt[j] - icol;
                float w = (delta >= 0 && delta < CTX_W) ? rowf[j] * colf : 0.f;
                wsum[j] += w;
                Ps[wq * 16 + rg * 4 + j][n * 16 + c] = f2bf(w * s[n][j]);
            }
        }
        #pragma unroll
        for (int u = 0; u < 2; ++u) {
            bf16x8_t pa = *(const bf16x8_t*)&Ps[wq * 16 + fr][u * 32 + fko];
            #pragma unroll
            for (int n = 0; n < 4; ++n) {
                bf16x8_t kb = *(const bf16x8_t*)&Xt[0][n * 16 + fr][u * 32 + fko];
                accc[n] = __builtin_amdgcn_mfma_f32_16x16x32_bf16(pa, kb, accc[n], 0, 0, 0);
            }
        }
        __syncthreads();
    }
    // persist = Q @ M_p^T
    f32x4_t pacc[4];
    #pragma unroll
    for (int n = 0; n < 4; ++n) pacc[n] = (f32x4_t)0.f;
    const float* mph = mp + hD * HD_DIM;
    #pragma unroll
    for (int u = 0; u < 2; ++u)
        #pragma unroll
        for (int n = 0; n < 4; ++n) {
            const float* br = mph + (size_t)(n * 16 + fr) * HD_DIM + u * 32 + fko;
            float4 a = *(const float4*)br;
            float4 b = *(const float4*)(br + 4);
            bf16x8_t f;
            f[0]=f2bf(a.x); f[1]=f2bf(a.y); f[2]=f2bf(a.z); f[3]=f2bf(a.w);
            f[4]=f2bf(b.x); f[5]=f2bf(b.y); f[6]=f2bf(b.z); f[7]=f2bf(b.w);
            pacc[n] = __builtin_amdgcn_mfma_f32_16x16x32_bf16(qf[u], f, pacc[n], 0, 0, 0);
        }
    #pragma unroll
    for (int j = 0; j < 4; ++j) {
        wsum[j] += __shfl_xor(wsum[j], 1);
        wsum[j] += __shfl_xor(wsum[j], 2);
        wsum[j] += __shfl_xor(wsum[j], 4);
        wsum[j] += __shfl_xor(wsum[j], 8);
    }
    float gate = 1.f / (1.f + __expf(-mg[0]));
    float keep = 1.f - gate;
    // q_new -> wave-private LDS rows (C-layout), then re-read as A-frags
    #pragma unroll
    for (int n = 0; n < 4; ++n) {
        #pragma unroll
        for (int j = 0; j < 4; ++j) {
            float qold = qhp[(hS + rowt[j]) * HD_DIM + n * 16 + c];
            float qn = keep * qold + gate * (pacc[n][j] + accc[n][j]) / (1.f + wsum[j]);
            Ps[wq * 16 + rg * 4 + j][n * 16 + c] = f2bf(qn);
        }
    }
    bf16x8_t qf2[2];
    #pragma unroll
    for (int u = 0; u < 2; ++u)
        qf2[u] = *(const bf16x8_t*)&Ps[wq * 16 + fr][u * 32 + fko];

    // ---------------- attention phase (double-buffered) ----------------
    f32x4_t acco[4];
    #pragma unroll
    for (int n = 0; n < 4; ++n) acco[n] = (f32x4_t)0.f;
    float m_run[4] = {-1e30f, -1e30f, -1e30f, -1e30f};
    float l_run[4] = {0.f, 0.f, 0.f, 0.f};
    {   // prologue: stage tile 0 (safe: omega loop ended with a barrier)
        const u16* gk = khp + (hS + si) * HD_DIM + sdb;
        const u16* gv = vhT + (hD + si) * S_LEN + sdb;
        bf16x8_t a0 = *(const bf16x8_t*)gk;
        bf16x8_t a1 = *(const bf16x8_t*)(gk + 8);
        bf16x8_t b0 = *(const bf16x8_t*)gv;
        bf16x8_t b1 = *(const bf16x8_t*)(gv + 8);
        *(bf16x8_t*)&Ks[0][si][sdb]     = a0;
        *(bf16x8_t*)&Ks[0][si][sdb + 8] = a1;
        *(bf16x8_t*)&Xt[0][si][sdb]     = b0;
        *(bf16x8_t*)&Xt[0][si][sdb + 8] = b1;
    }
    __syncthreads();
    int cur = 0;
    for (int kt = 0; kt <= qt; ++kt) {
        const int k0 = kt * KBLK;
        bf16x8_t nk0, nk1, nv0, nv1;
        const bool hn = (kt < qt);
        if (hn) {  // issue next-tile loads early; latency hides under compute
            const u16* gk = khp + (hS + k0 + KBLK + si) * HD_DIM + sdb;
            const u16* gv = vhT + (hD + si) * S_LEN + k0 + KBLK + sdb;
            nk0 = *(const bf16x8_t*)gk; nk1 = *(const bf16x8_t*)(gk + 8);
            nv0 = *(const bf16x8_t*)gv; nv1 = *(const bf16x8_t*)(gv + 8);
        }
        f32x4_t s[4];
        #pragma unroll
        for (int n = 0; n < 4; ++n) s[n] = (f32x4_t)0.f;
        #pragma unroll
        for (int u = 0; u < 2; ++u)
            #pragma unroll
            for (int n = 0; n < 4; ++n) {
                bf16x8_t kb = *(const bf16x8_t*)&Ks[cur][n * 16 + fr][u * 32 + fko];
                s[n] = __builtin_amdgcn_mfma_f32_16x16x32_bf16(qf2[u], kb, s[n], 0, 0, 0);
            }
        float tmax[4] = {-1e30f, -1e30f, -1e30f, -1e30f};
        #pragma unroll
        for (int n = 0; n < 4; ++n) {
            int icol = k0 + n * 16 + c;
            #pragma unroll
            for (int j = 0; j < 4; ++j) {
                float v = s[n][j] * 0.125f;
                if (icol > rowt[j]) v = -1e30f;
                s[n][j] = v;
                tmax[j] = fmaxf(tmax[j], v);
            }
        }
        #pragma unroll
        for (int j = 0; j < 4; ++j) {
            tmax[j] = fmaxf(tmax[j], __shfl_xor(tmax[j], 1));
            tmax[j] = fmaxf(tmax[j], __shfl_xor(tmax[j], 2));
            tmax[j] = fmaxf(tmax[j], __shfl_xor(tmax[j], 4));
            tmax[j] = fmaxf(tmax[j], __shfl_xor(tmax[j], 8));
        }
        float corr[4];
        #pragma unroll
        for (int j = 0; j < 4; ++j) {
            float mn = fmaxf(m_run[j], tmax[j]);
            corr[j] = __expf(m_run[j] - mn);
            m_run[j] = mn;
            l_run[j] *= corr[j];
        }
        #pragma unroll
        for (int n = 0; n < 4; ++n)
            #pragma unroll
            for (int j = 0; j < 4; ++j) acco[n][j] *= corr[j];
        #pragma unroll
        for (int n = 0; n < 4; ++n) {
            #pragma unroll
            for (int j = 0; j < 4; ++j) {
                float p = __expf(s[n][j] - m_run[j]);
                l_run[j] += p;
                Ps[wq * 16 + rg * 4 + j][n * 16 + c] = f2bf(p);
            }
        }
        #pragma unroll
        for (int u = 0; u < 2; ++u) {
            bf16x8_t pa = *(const bf16x8_t*)&Ps[wq * 16 + fr][u * 32 + fko];
            #pragma unroll
            for (int n = 0; n < 4; ++n) {
                bf16x8_t vb = *(const bf16x8_t*)&Xt[cur][n * 16 + fr][u * 32 + fko];
                acco[n] = __builtin_amdgcn_mfma_f32_16x16x32_bf16(pa, vb, acco[n], 0, 0, 0);
            }
        }
        if (hn) {  // write-late into the other buffer
            int nxt = cur ^ 1;
            *(bf16x8_t*)&Ks[nxt][si][sdb]     = nk0;
            *(bf16x8_t*)&Ks[nxt][si][sdb + 8] = nk1;
            *(bf16x8_t*)&Xt[nxt][si][sdb]     = nv0;
            *(bf16x8_t*)&Xt[nxt][si][sdb + 8] = nv1;
        }
        __syncthreads();
        cur ^= 1;
    }
    #pragma unroll
    for (int j = 0; j < 4; ++j) {
        l_run[j] += __shfl_xor(l_run[j], 1);
        l_run[j] += __shfl_xor(l_run[j], 2);
        l_run[j] += __shfl_xor(l_run[j], 4);
        l_run[j] += __shfl_xor(l_run[j], 8);
    }
    #pragma unroll
    for (int n = 0; n < 4; ++n) {
        #pragma unroll
        for (int j = 0; j < 4; ++j) {
            float o = acco[n][j] / l_run[j];
            ao[(size_t)rowt[j] * D_DIM + h * HD_DIM + n * 16 + c] = f2bf(o);
        }
    }
}

// ------------- fused SwiGLU: mid = silu(G1)*G3 (bf16 in/out, padded) --------
__global__ __launch_bounds__(256) void silumul_bf_kernel(const u16* __restrict__ G,
    u16* __restrict__ mid)
{
    int m = blockIdx.x;
    const u16* g1 = G + (size_t)m * (2 * FFNP);
    const u16* g3 = g1 + FFNP;
    u16* mo = mid + (size_t)m * FFNP;
    for (int ci = threadIdx.x; ci < FFNP / 8; ci += 256) {
        bf16x8_t a = *(const bf16x8_t*)(g1 + ci * 8);
        bf16x8_t b = *(const bf16x8_t*)(g3 + ci * 8);
        bf16x8_t o;
        #pragma unroll
        for (int e = 0; e < 8; ++e) {
            float fa = bf2f((u16)a[e]);
            float fb = bf2f((u16)b[e]);
            o[e] = (short)f2bf(fa / (1.f + __expf(-fa)) * fb);
        }
        *(bf16x8_t*)(mo + ci * 8) = o;
    }
}

extern "C" void kernel_launch(void* const* d_in, const int* in_sizes, int n_in,
                              void* d_out, int out_size, void* d_ws, size_t ws_size,
                              hipStream_t stream) {
    const float* x         = (const float*)d_in[0];
    const float* norm1_w   = (const float*)d_in[1];
    const float* norm2_w   = (const float*)d_in[2];
    const float* w_qkv     = (const float*)d_in[3];
    const float* q_norm_w  = (const float*)d_in[4];
    const float* k_norm_w  = (const float*)d_in[5];
    const float* gamma_w1  = (const float*)d_in[6];
    const float* gamma_w2  = (const float*)d_in[7];
    const float* m_persist = (const float*)d_in[8];
    const float* mem_gate  = (const float*)d_in[9];
    const float* w_o       = (const float*)d_in[10];
    const float* ffn_w1    = (const float*)d_in[11];
    const float* ffn_w3    = (const float*)d_in[12];
    const float* ffn_w2    = (const float*)d_in[13];
    float* out = (float*)d_out;
    char* ws = (char*)d_ws;

    const size_t MB = 1024 * 1024;
    u16*   h_bf   = (u16*)(ws);                 // [0,4MB) h / h2
    u16*   wqT    = (u16*)(ws + 4 * MB);        // [4,10)
    u16*   woT    = (u16*)(ws + 10 * MB);       // [10,12)
    u16*   w13T   = (u16*)(ws + 12 * MB);       // [12,23)
    u16*   w2T    = (u16*)(ws + 23 * MB);       // [23,28.5)
    u16*   qkv_bf = (u16*)(ws + 29884416);      // [28.5,40.5) dead after split
    u16*   khT    = (u16*)(ws + 29884416);      // [28.5,32.5) (qkv region, post-split)
    u16*   vhT    = (u16*)(ws + 34078720);      // [32.5,36.5)
    u16*   ao_bf  = (u16*)(ws + 38273024);      // [36.5,40.5)
    float* qh     = (float*)(ws + 42467328);    // [40.5,48.5) fp32 q
    u16*   kh     = (u16*)(ws + 50855936);      // [48.5,52.5)
    u16*   vh     = (u16*)(ws + 55050240);      // [52.5,56.5)
    float* gammab = (float*)(ws + 59244544);    // [56.5,+8KB)
    u16*   G_bf   = (u16*)(ws + 29884416);      // [28.5,50.5) post-attention
    u16*   mid_bf = (u16*)(ws + 4 * MB);        // [4,15) post-ffn13

    // --- weight transposes/conversions ---------------------------------------
    hipLaunchKernelGGL(transpose_cvt_kernel, dim3(96, 32), dim3(256), 0, stream,
                       w_qkv, wqT, D_DIM, 3 * D_DIM, D_DIM, 0);
    hipLaunchKernelGGL(transpose_cvt_kernel, dim3(32, 32), dim3(256), 0, stream,
                       w_o, woT, D_DIM, D_DIM, D_DIM, 0);
    hipLaunchKernelGGL(transpose_cvt_kernel, dim3(88, 32), dim3(256), 0, stream,
                       ffn_w1, w13T, D_DIM, FFN_H, D_DIM, 0);
    hipLaunchKernelGGL(transpose_cvt_kernel, dim3(88, 32), dim3(256), 0, stream,
                       ffn_w3, w13T, D_DIM, FFN_H, D_DIM, FFNP);
    hipLaunchKernelGGL(transpose_cvt_kernel, dim3(32, 88), dim3(256), 0, stream,
                       ffn_w2, w2T, FFN_H, D_DIM, FFNP, 0);

    // --- forward pass ---------------------------------------------------------
    hipLaunchKernelGGL(rmsnorm_bf_kernel, dim3(S_LEN), dim3(256), 0, stream,
                       x, norm1_w, h_bf);
    hipLaunchKernelGGL((gemm_bb_kernel<128, true, false>), dim3(24, 16), dim3(256), 0, stream,
                       h_bf, wqT, (const float*)nullptr, (float*)nullptr, qkv_bf,
                       S_LEN, 3 * D_DIM, D_DIM);
    hipLaunchKernelGGL(split_rope_kernel, dim3(S_LEN / 4, H_NUM), dim3(256), 0, stream,
                       qkv_bf, q_norm_w, k_norm_w, qh, kh, vh);
    hipLaunchKernelGGL(transpose_kv_kernel, dim3(S_LEN / 64, H_NUM), dim3(256), 0, stream,
                       kh, vh, khT, vhT);
    hipLaunchKernelGGL(gamma_kernel, dim3(S_LEN), dim3(256), 0, stream,
                       h_bf, gamma_w1, gamma_w2, gammab);
    hipLaunchKernelGGL(fused_omega_attn_kernel, dim3(S_LEN / QBLK, H_NUM), dim3(256), 0, stream,
                       qh, kh, khT, vhT, gammab, m_persist, mem_gate, ao_bf);
    hipLaunchKernelGGL((gemm_bb_kernel<64, false, true>), dim3(8, 32), dim3(256), 0, stream,
                       ao_bf, woT, x, out, (u16*)nullptr, S_LEN, D_DIM, D_DIM);
    hipLaunchKernelGGL(rmsnorm_bf_kernel, dim3(S_LEN), dim3(256), 0, stream,
                       out, norm2_w, h_bf);
    hipLaunchKernelGGL((gemm_bb_kernel<128, true, false>), dim3(44, 16), dim3(256), 0, stream,
                       h_bf, w13T, (const float*)nullptr, (float*)nullptr, G_bf,
                       S_LEN, 2 * FFNP, D_DIM);
    hipLaunchKernelGGL(silumul_bf_kernel, dim3(S_LEN), dim3(256), 0, stream,
                       G_bf, mid_bf);
    hipLaunchKernelGGL((gemm_bb_kernel<64, false, true>), dim3(8, 32), dim3(256), 0, stream,
                       mid_bf, w2T, out, out, (u16*)nullptr, S_LEN, D_DIM, FFNP);
}